// Round 1
// baseline (637.345 us; speedup 1.0000x reference)
//
#include <hip/hip_runtime.h>
#include <stdint.h>

// Flip to 0 if the harness JAX predates jax_threefry_partitionable=True default.
#define PARTITIONABLE 1

namespace {

constexpr int Bn = 16, Tn = 512, Dn = 256, Hn = 4, MCn = 4, DHn = 128;
constexpr int GSn = 4, SSn = 6, ASn = 4, DECHn = 128;

// ---------------- Threefry-2x32 (constexpr, host+device) ----------------
struct TFPair { uint32_t a, b; };

__host__ __device__ constexpr uint32_t rotl32(uint32_t x, int d) {
  return (x << d) | (x >> (32 - d));
}

__host__ __device__ constexpr TFPair tf2x32(uint32_t k0, uint32_t k1,
                                            uint32_t x0, uint32_t x1) {
  uint32_t k2 = k0 ^ k1 ^ 0x1BD11BDAu;
  x0 += k0; x1 += k1;
  x0 += x1; x1 = rotl32(x1, 13); x1 ^= x0;
  x0 += x1; x1 = rotl32(x1, 15); x1 ^= x0;
  x0 += x1; x1 = rotl32(x1, 26); x1 ^= x0;
  x0 += x1; x1 = rotl32(x1, 6);  x1 ^= x0;
  x0 += k1; x1 += k2 + 1u;
  x0 += x1; x1 = rotl32(x1, 17); x1 ^= x0;
  x0 += x1; x1 = rotl32(x1, 29); x1 ^= x0;
  x0 += x1; x1 = rotl32(x1, 16); x1 ^= x0;
  x0 += x1; x1 = rotl32(x1, 24); x1 ^= x0;
  x0 += k2; x1 += k0 + 2u;
  x0 += x1; x1 = rotl32(x1, 13); x1 ^= x0;
  x0 += x1; x1 = rotl32(x1, 15); x1 ^= x0;
  x0 += x1; x1 = rotl32(x1, 26); x1 ^= x0;
  x0 += x1; x1 = rotl32(x1, 6);  x1 ^= x0;
  x0 += k0; x1 += k1 + 3u;
  x0 += x1; x1 = rotl32(x1, 17); x1 ^= x0;
  x0 += x1; x1 = rotl32(x1, 29); x1 ^= x0;
  x0 += x1; x1 = rotl32(x1, 16); x1 ^= x0;
  x0 += x1; x1 = rotl32(x1, 24); x1 ^= x0;
  x0 += k1; x1 += k2 + 4u;
  x0 += x1; x1 = rotl32(x1, 13); x1 ^= x0;
  x0 += x1; x1 = rotl32(x1, 15); x1 ^= x0;
  x0 += x1; x1 = rotl32(x1, 26); x1 ^= x0;
  x0 += x1; x1 = rotl32(x1, 6);  x1 ^= x0;
  x0 += k2; x1 += k0 + 5u;
  return TFPair{x0, x1};
}

// master key = jax.random.key(42) -> (0, 42)
#if PARTITIONABLE
// split(key,n): key_i = threefry(key, (0, i)) (both output words)
constexpr TFPair KG  = tf2x32(0u, 42u, 0u, 0u);
constexpr TFPair KS  = tf2x32(0u, 42u, 0u, 1u);
constexpr TFPair KA  = tf2x32(0u, 42u, 0u, 2u);
constexpr TFPair KE  = tf2x32(0u, 42u, 0u, 3u);
constexpr TFPair KD  = tf2x32(0u, 42u, 0u, 4u);
constexpr TFPair DK0 = tf2x32(KD.a, KD.b, 0u, 0u);
constexpr TFPair DK1 = tf2x32(KD.a, KD.b, 0u, 1u);
constexpr TFPair DK2 = tf2x32(KD.a, KD.b, 0u, 2u);
#else
// original mode: split via iota pairing
constexpr TFPair SP0 = tf2x32(0u, 42u, 0u, 5u);
constexpr TFPair SP1 = tf2x32(0u, 42u, 1u, 6u);
constexpr TFPair SP2 = tf2x32(0u, 42u, 2u, 7u);
constexpr TFPair SP3 = tf2x32(0u, 42u, 3u, 8u);
constexpr TFPair SP4 = tf2x32(0u, 42u, 4u, 9u);
constexpr TFPair KG  = TFPair{SP0.a, SP1.a};
constexpr TFPair KS  = TFPair{SP2.a, SP3.a};
constexpr TFPair KA  = TFPair{SP4.a, SP0.b};
constexpr TFPair KE  = TFPair{SP1.b, SP2.b};
constexpr TFPair KD  = TFPair{SP3.b, SP4.b};
constexpr TFPair DP0 = tf2x32(KD.a, KD.b, 0u, 3u);
constexpr TFPair DP1 = tf2x32(KD.a, KD.b, 1u, 4u);
constexpr TFPair DP2 = tf2x32(KD.a, KD.b, 2u, 5u);
constexpr TFPair DK0 = TFPair{DP0.a, DP1.a};
constexpr TFPair DK1 = TFPair{DP2.a, DP0.b};
constexpr TFPair DK2 = TFPair{DP1.b, DP2.b};
#endif

__device__ __forceinline__ uint32_t rbits(uint32_t k0, uint32_t k1,
                                          uint32_t idx, uint32_t half) {
#if PARTITIONABLE
  TFPair t = tf2x32(k0, k1, 0u, idx);
  return t.a ^ t.b;
#else
  if (idx < half) return tf2x32(k0, k1, idx, idx + half).a;
  return tf2x32(k0, k1, idx - half, idx).b;
#endif
}

__device__ __forceinline__ float bits_to_u01(uint32_t bits) {
  return __uint_as_float((bits >> 9) | 0x3F800000u) - 1.0f;
}

// jax.random.uniform(key, minval=1e-6, maxval=1-1e-6) at flat index idx
__device__ __forceinline__ float gumbel_u(uint32_t k0, uint32_t k1,
                                          uint32_t idx, uint32_t half) {
  const float mn = 1e-6f;
  const float mx = 1.0f - 1e-6f;
  float f = bits_to_u01(rbits(k0, k1, idx, half));
  return fmaxf(mn, f * (mx - mn) + mn);
}

// XLA f32 erf_inv (Giles polynomial)
__device__ __forceinline__ float erfinv_f32(float x) {
  float w = -log1pf(-x * x);
  float p;
  if (w < 5.0f) {
    w -= 2.5f;
    p = 2.81022636e-08f;
    p = fmaf(p, w, 3.43273939e-07f);
    p = fmaf(p, w, -3.5233877e-06f);
    p = fmaf(p, w, -4.39150654e-06f);
    p = fmaf(p, w, 0.00021858087f);
    p = fmaf(p, w, -0.00125372503f);
    p = fmaf(p, w, -0.00417768164f);
    p = fmaf(p, w, 0.246640727f);
    p = fmaf(p, w, 1.50140941f);
  } else {
    w = sqrtf(w) - 3.0f;
    p = -0.000200214257f;
    p = fmaf(p, w, 0.000100950558f);
    p = fmaf(p, w, 0.00134934322f);
    p = fmaf(p, w, -0.00367342844f);
    p = fmaf(p, w, 0.00573950773f);
    p = fmaf(p, w, -0.0076224613f);
    p = fmaf(p, w, 0.00943887047f);
    p = fmaf(p, w, 1.00167406f);
    p = fmaf(p, w, 2.83297682f);
  }
  return p * x;
}

// jax.random.normal at flat index idx
__device__ __forceinline__ float normal_from(uint32_t k0, uint32_t k1,
                                             uint32_t idx, uint32_t half) {
  const float lo = -0x1.fffffep-1f;  // nextafter(-1, 0)
  float f = bits_to_u01(rbits(k0, k1, idx, half));
  float u = fmaxf(lo, f * 2.0f + lo);  // (1.0 - lo) rounds to 2.0f
  return 1.41421356237f * erfinv_f32(u);
}

__device__ __forceinline__ float gelu_f(float x) {
  return 0.5f * x * (1.0f + erff(x / 1.4142135623730951f));
}
__device__ __forceinline__ float sigmoid_f(float x) {
  return 1.0f / (1.0f + expf(-x));
}

// ---------------- block reductions ----------------
template <int NT>
__device__ __forceinline__ float bsum(float v, float* red) {
  int t = threadIdx.x;
  red[t] = v; __syncthreads();
  #pragma unroll
  for (int s = NT >> 1; s > 0; s >>= 1) {
    if (t < s) red[t] += red[t + s];
    __syncthreads();
  }
  float r = red[0]; __syncthreads();
  return r;
}
template <int NT>
__device__ __forceinline__ float bmax(float v, float* red) {
  int t = threadIdx.x;
  red[t] = v; __syncthreads();
  #pragma unroll
  for (int s = NT >> 1; s > 0; s >>= 1) {
    if (t < s) red[t] = fmaxf(red[t], red[t + s]);
    __syncthreads();
  }
  float r = red[0]; __syncthreads();
  return r;
}

// ---------------- kernels ----------------

// seq_mean + telescoped diff_summary. grid 64 x 64 threads.
__global__ void k_reduce_x(const float* __restrict__ x, float* __restrict__ sm,
                           float* __restrict__ ds) {
  int b = blockIdx.x >> 2;
  int d = ((blockIdx.x & 3) << 6) + threadIdx.x;
  const float* xb = x + (size_t)b * Tn * Dn + d;
  float s = 0.f;
  for (int t = 0; t < Tn; ++t) s += xb[(size_t)t * Dn];
  sm[b * Dn + d] = s / 512.0f;
  ds[b * Dn + d] = (xb[(size_t)(Tn - 1) * Dn] - xb[0]) / 511.0f;
}

// global head: MLP + LN + gelu + logits + gumbel-softmax -> g_probs (B,4)
__global__ __launch_bounds__(256) void k_g_head(
    const float* __restrict__ sm, const float* __restrict__ gW1,
    const float* __restrict__ gb1, const float* __restrict__ glnw,
    const float* __restrict__ glnb, const float* __restrict__ gW2,
    const float* __restrict__ gb2, float* __restrict__ gprobs) {
  __shared__ float red[256];
  __shared__ float smv[256];
  __shared__ float hg[256];
  __shared__ float lg[GSn];
  __shared__ float vals[GSn];
  int b = blockIdx.x, j = threadIdx.x;
  smv[j] = sm[b * 256 + j];
  __syncthreads();
  float h = gb1[j];
  for (int d = 0; d < 256; ++d) h = fmaf(smv[d], gW1[d * 256 + j], h);
  float mean = bsum<256>(h, red) / 256.0f;
  float dv = h - mean;
  float var = bsum<256>(dv * dv, red) / 256.0f;
  float hn = dv / sqrtf(var + 1e-5f) * glnw[j] + glnb[j];
  hg[j] = gelu_f(hn);
  __syncthreads();
  if (j < GSn) {
    float l = gb2[j];
    for (int d = 0; d < 256; ++d) l = fmaf(hg[d], gW2[d * GSn + j], l);
    lg[j] = l;
  }
  __syncthreads();
  if (j < GSn) {
    float u = gumbel_u(KG.a, KG.b, (uint32_t)(b * GSn + j), 32u);
    float g = -logf(-logf(u));
    vals[j] = (lg[j] + g) / 0.5f;
  }
  __syncthreads();
  if (j < GSn) {
    float mx = vals[0];
    #pragma unroll
    for (int s = 1; s < GSn; ++s) mx = fmaxf(mx, vals[s]);
    float sum = 0.f;
    #pragma unroll
    for (int s = 0; s < GSn; ++s) sum += expf(vals[s] - mx);
    gprobs[b * GSn + j] = expf(vals[j] - mx) / sum;
  }
}

// sector head -> sector_gate (B,D)
__global__ __launch_bounds__(256) void k_s_head(
    const float* __restrict__ sm, const float* __restrict__ sW1,
    const float* __restrict__ sb1, const float* __restrict__ sW2,
    const float* __restrict__ sb2, const float* __restrict__ semb,
    float* __restrict__ sgate) {
  __shared__ float smv[256];
  __shared__ float hg[256];
  int b = blockIdx.x, j = threadIdx.x;
  smv[j] = sm[b * 256 + j];
  __syncthreads();
  float h = sb1[j];
  for (int d = 0; d < 256; ++d) h = fmaf(smv[d], sW1[d * 256 + j], h);
  hg[j] = gelu_f(h);
  __syncthreads();
  int f = j;
  float lg[SSn];
  #pragma unroll
  for (int s = 0; s < SSn; ++s) lg[s] = sb2[f * SSn + s];
  for (int d = 0; d < 256; ++d) {
    float hd = hg[d];
    const float* w = sW2 + (size_t)d * (Dn * SSn) + f * SSn;
    #pragma unroll
    for (int s = 0; s < SSn; ++s) lg[s] = fmaf(hd, w[s], lg[s]);
  }
  uint32_t base = (uint32_t)(b * 256 + f) * SSn;
  float vals[SSn];
  #pragma unroll
  for (int s = 0; s < SSn; ++s) {
    float u = gumbel_u(KS.a, KS.b, base + s, 12288u);
    float g = -logf(-logf(u));
    vals[s] = (lg[s] + g) / 0.5f;
  }
  float mx = vals[0];
  #pragma unroll
  for (int s = 1; s < SSn; ++s) mx = fmaxf(mx, vals[s]);
  float sum = 0.f;
  #pragma unroll
  for (int s = 0; s < SSn; ++s) { vals[s] = expf(vals[s] - mx); sum += vals[s]; }
  float sg = 0.f;
  #pragma unroll
  for (int s = 0; s < SSn; ++s) sg += (vals[s] / sum) * semb[s * Dn + f];
  sgate[b * 256 + f] = sg;
}

// asset head -> asset_gate (B,D)
__global__ __launch_bounds__(256) void k_a_head(
    const float* __restrict__ ds, const float* __restrict__ aW1,
    const float* __restrict__ ab1, const float* __restrict__ aW2,
    const float* __restrict__ ab2, const float* __restrict__ aemb,
    float* __restrict__ agate) {
  __shared__ float dsv[256];
  __shared__ float hg[256];
  int b = blockIdx.x, j = threadIdx.x;
  dsv[j] = ds[b * 256 + j];
  __syncthreads();
  float h = ab1[j];
  for (int d = 0; d < 256; ++d) h = fmaf(dsv[d], aW1[d * 256 + j], h);
  hg[j] = gelu_f(h);
  __syncthreads();
  int f = j;
  float lg[ASn];
  #pragma unroll
  for (int s = 0; s < ASn; ++s) lg[s] = ab2[f * ASn + s];
  for (int d = 0; d < 256; ++d) {
    float hd = hg[d];
    const float* w = aW2 + (size_t)d * (Dn * ASn) + f * ASn;
    #pragma unroll
    for (int s = 0; s < ASn; ++s) lg[s] = fmaf(hd, w[s], lg[s]);
  }
  uint32_t base = (uint32_t)(b * 256 + f) * ASn;
  float vals[ASn];
  #pragma unroll
  for (int s = 0; s < ASn; ++s) {
    float u = gumbel_u(KA.a, KA.b, base + s, 8192u);
    float g = -logf(-logf(u));
    vals[s] = (lg[s] + g) / 0.5f;
  }
  float mx = vals[0];
  #pragma unroll
  for (int s = 1; s < ASn; ++s) mx = fmaxf(mx, vals[s]);
  float sum = 0.f;
  #pragma unroll
  for (int s = 0; s < ASn; ++s) { vals[s] = expf(vals[s] - mx); sum += vals[s]; }
  float ag = 0.f;
  #pragma unroll
  for (int s = 0; s < ASn; ++s) ag += (vals[s] / sum) * aemb[s * Dn + f];
  agate[b * 256 + f] = ag;
}

// feature_gate = sigmoid(g_probs@g2f + sector_gate + asset_gate)
__global__ void k_fgate(const float* __restrict__ gprobs,
                        const float* __restrict__ g2f,
                        const float* __restrict__ sgate,
                        const float* __restrict__ agate,
                        float* __restrict__ fg) {
  int idx = blockIdx.x * 256 + threadIdx.x;  // (b,f)
  int b = idx >> 8, f = idx & 255;
  float gg = 0.f;
  #pragma unroll
  for (int s = 0; s < GSn; ++s) gg = fmaf(gprobs[b * GSn + s], g2f[s * Dn + f], gg);
  fg[idx] = sigmoid_f(gg + sgate[idx] + agate[idx]);
}

// ctx = normalize(mean_b(feature_gate)); ctx[256] = sum(ctx)
__global__ __launch_bounds__(256) void k_ctx(const float* __restrict__ fg,
                                             float* __restrict__ ctx) {
  __shared__ float red[256];
  int f = threadIdx.x;
  float c = 0.f;
  for (int b = 0; b < Bn; ++b) c += fg[b * Dn + f];
  c /= 16.0f;
  float ss = bsum<256>(c * c, red);
  float cv = c / (sqrtf(ss) + 1e-6f);
  ctx[f] = cv;
  float S = bsum<256>(cv, red);
  if (f == 0) ctx[256] = S;
}

// bidirectional EMA scan on gated x -> hsum (B,T,D). grid 64 x 64 threads.
__global__ void k_scan(const float* __restrict__ x, const float* __restrict__ fg,
                       const float* __restrict__ decay_f,
                       const float* __restrict__ decay_b,
                       float* __restrict__ hsum) {
  int b = blockIdx.x >> 2;
  int d = ((blockIdx.x & 3) << 6) + threadIdx.x;
  float g = fg[b * Dn + d];
  float af = sigmoid_f(decay_f[d]);
  float ab = sigmoid_f(decay_b[d]);
  const float* xb = x + (size_t)b * Tn * Dn + d;
  float* hb = hsum + (size_t)b * Tn * Dn + d;
  float h = 0.f;
  for (int t = 0; t < Tn; ++t) {
    float gx = xb[(size_t)t * Dn] * g;
    h = af * h + (1.0f - af) * gx;
    hb[(size_t)t * Dn] = h;
  }
  h = 0.f;
  for (int t = Tn - 1; t >= 0; --t) {
    float gx = xb[(size_t)t * Dn] * g;
    h = ab * h + (1.0f - ab) * gx;
    hb[(size_t)t * Dn] += h;
  }
}

// generic fp32 tiled GEMM: C[b] = A[b](MxK) @ B[b](KxN) (+init)(+bias)
// TRANS: store as (N x M) with ld=M (used for node_major transpose)
template <bool TRANS, bool BIAS, bool INIT>
__global__ __launch_bounds__(256) void gemm_f32(
    const float* __restrict__ Aall, size_t sA, const float* __restrict__ Ball,
    size_t sB, float* __restrict__ Call, size_t sC,
    const float* __restrict__ Iall, size_t sI, const float* __restrict__ bias,
    int M, int N, int Kd) {
  const float* A = Aall + (size_t)blockIdx.z * sA;
  const float* Bm = Ball + (size_t)blockIdx.z * sB;
  float* C = Call + (size_t)blockIdx.z * sC;
  const int n0 = blockIdx.x * 32;
  const int m0 = blockIdx.y * 32;
  __shared__ float As[32][33];
  __shared__ float Bs[32][33];
  const int tid = threadIdx.x;
  const int tx = tid & 31;
  const int ty = tid >> 5;
  float acc[4] = {0.f, 0.f, 0.f, 0.f};
  for (int k0 = 0; k0 < Kd; k0 += 32) {
    #pragma unroll
    for (int i = 0; i < 4; ++i) {
      int e = tid + i * 256;
      int r = e >> 5, c = e & 31;
      As[r][c] = A[(size_t)(m0 + r) * Kd + k0 + c];
      Bs[r][c] = Bm[(size_t)(k0 + r) * N + n0 + c];
    }
    __syncthreads();
    #pragma unroll
    for (int kk = 0; kk < 32; ++kk) {
      float bv = Bs[kk][tx];
      #pragma unroll
      for (int i = 0; i < 4; ++i)
        acc[i] = fmaf(As[ty + 8 * i][kk], bv, acc[i]);
    }
    __syncthreads();
  }
  if (INIT) {
    const float* I = Iall + (size_t)blockIdx.z * sI;
    #pragma unroll
    for (int i = 0; i < 4; ++i)
      acc[i] += I[(size_t)(m0 + ty + 8 * i) * N + n0 + tx];
  }
  if (!TRANS) {
    #pragma unroll
    for (int i = 0; i < 4; ++i) {
      float v = acc[i];
      if (BIAS) v += bias[n0 + tx];
      C[(size_t)(m0 + ty + 8 * i) * N + n0 + tx] = v;
    }
  } else {
    #pragma unroll
    for (int i = 0; i < 4; ++i) As[ty + 8 * i][tx] = acc[i];
    __syncthreads();
    #pragma unroll
    for (int i = 0; i < 4; ++i) {
      int e = tid + i * 256;
      int nl = e >> 5, ml = e & 31;
      float v = As[ml][nl];
      if (BIAS) v += bias[n0 + nl];
      C[(size_t)(n0 + nl) * M + m0 + ml] = v;
    }
  }
}

// adjacency logits L[h,n,m] = psi[h,n,:]·psi[h,m,:] / sqrt(10)
__global__ void k_adj(const float* __restrict__ psi, float* __restrict__ L) {
  int hn = blockIdx.x;
  int h = hn >> 8, n = hn & 255, m = threadIdx.x;
  __shared__ float pn[10];
  if (m < 10) pn[m] = psi[(size_t)(h * 256 + n) * 10 + m];
  __syncthreads();
  const float* pm = psi + (size_t)(h * 256 + m) * 10;
  float s = 0.f;
  #pragma unroll
  for (int e = 0; e < 10; ++e) s = fmaf(pn[e], pm[e], s);
  L[(size_t)hn * 256 + m] = s / sqrtf(10.0f);
}

// A = softmax(L + sigma*eps) over last axis; one block per (m,h,n) row
__global__ __launch_bounds__(256) void k_a_init(const float* __restrict__ L,
                                                const float* __restrict__ log_sigma,
                                                float* __restrict__ A) {
  __shared__ float red[256];
  int blk = blockIdx.x;           // mh*256 + n
  int mh = blk >> 8, h = mh & 3, p = threadIdx.x;
  int n = blk & 255;
  uint32_t idx = (uint32_t)blk * 256u + (uint32_t)p;
  float eps = normal_from(KE.a, KE.b, idx, 524288u);
  float v = L[(size_t)(h * 256 + n) * 256 + p] + expf(log_sigma[h]) * eps;
  float mx = bmax<256>(v, red);
  float e = expf(v - mx);
  float sum = bsum<256>(e, red);
  A[(size_t)blk * 256 + p] = e / sum;
}

// diffusion mix: Atmp = alpha*A + (1-alpha)*outer + noise
__global__ void k_mix(const float* __restrict__ A, float* __restrict__ Atmp,
                      const float* __restrict__ ctx,
                      const float* __restrict__ step_logits,
                      const float* __restrict__ noise_scale, int s,
                      uint32_t dk0, uint32_t dk1) {
  uint32_t idx = blockIdx.x * 256u + threadIdx.x;
  int p = idx & 255, n = (idx >> 8) & 255;
  float alpha = sigmoid_f(step_logits[s]);
  float ns = noise_scale[s];
  float cn = ctx[n], cp = ctx[p], S = ctx[256];
  float outer = (cn * cp) / fmaxf(cn * S, 1e-6f);
  float z = normal_from(dk0, dk1, idx, 524288u);
  Atmp[idx] = alpha * A[idx] + (1.0f - alpha) * outer + ns * z;
}

// symmetrize + row softmax
__global__ __launch_bounds__(256) void k_sym_softmax(const float* __restrict__ Atmp,
                                                     float* __restrict__ A) {
  __shared__ float red[256];
  int blk = blockIdx.x;
  int mh = blk >> 8, n = blk & 255, p = threadIdx.x;
  const float* M = Atmp + (size_t)mh * 65536;
  float v = 0.5f * (M[n * 256 + p] + M[p * 256 + n]);
  float mx = bmax<256>(v, red);
  float e = expf(v - mx);
  float sum = bsum<256>(e, red);
  A[(size_t)blk * 256 + p] = e / sum;
}

// S_k = mean over (m,h) of A^k; layout Scat[n*768 + (k-1)*256 + p]
__global__ void k_sreduce(const float* __restrict__ A1,
                          const float* __restrict__ A2,
                          const float* __restrict__ A3,
                          float* __restrict__ Scat) {
  int idx = blockIdx.x * 256 + threadIdx.x;  // 196608
  int n = idx / 768, r = idx % 768, k = r >> 8, p = r & 255;
  const float* src = (k == 0) ? A1 : (k == 1) ? A2 : A3;
  float s = 0.f;
  for (int mh = 0; mh < 16; ++mh) s += src[(size_t)mh * 65536 + n * 256 + p];
  Scat[idx] = s / 16.0f;
}

// graph_mean / graph_logvar heads
__global__ void k_graph_head(const float* __restrict__ Z,
                             const float* __restrict__ mean_w,
                             const float* __restrict__ mean_b,
                             const float* __restrict__ lv_w,
                             const float* __restrict__ lv_b,
                             float* __restrict__ gm, float* __restrict__ glv) {
  int idx = blockIdx.x * 256 + threadIdx.x;  // (b,n)
  const float* z = Z + (size_t)idx * DHn;
  float a = 0.f, c = 0.f;
  for (int d = 0; d < DHn; ++d) {
    a = fmaf(z[d], mean_w[d], a);
    c = fmaf(z[d], lv_w[d], c);
  }
  gm[idx] = a + mean_b[0];
  glv[idx] = c + lv_b[0];
}

// risk-aware decoder -> out (B,2)
__global__ __launch_bounds__(128) void k_decoder(
    const float* __restrict__ gm, const float* __restrict__ glv,
    const float* __restrict__ dW1, const float* __restrict__ db1,
    const float* __restrict__ dlnw, const float* __restrict__ dlnb,
    const float* __restrict__ mW, const float* __restrict__ mb,
    const float* __restrict__ lvW, const float* __restrict__ lvb,
    float* __restrict__ out) {
  __shared__ float red[128];
  __shared__ float gmv[256];
  int b = blockIdx.x, j = threadIdx.x;
  gmv[j] = gm[b * 256 + j];
  gmv[j + 128] = gm[b * 256 + j + 128];
  __syncthreads();
  float h = db1[j];
  for (int n = 0; n < 256; ++n) h = fmaf(gmv[n], dW1[n * 128 + j], h);
  h = gelu_f(h);
  float mean = bsum<128>(h, red) / 128.0f;
  float dv = h - mean;
  float var = bsum<128>(dv * dv, red) / 128.0f;
  float feat = dv / sqrtf(var + 1e-5f) * dlnw[j] + dlnb[j];
  float m_c = bsum<128>(feat * mW[j], red) + mb[0];
  float lv_c = bsum<128>(feat * lvW[j], red) + lvb[0];
  float se = expf(glv[b * 256 + j]) + expf(glv[b * 256 + j + 128]);
  float sumexp = bsum<128>(se, red);
  if (j == 0) {
    out[b * 2 + 0] = m_c;
    out[b * 2 + 1] = logf(expf(lv_c) + sumexp);
  }
}

// workspace layout (float offsets)
constexpr size_t O_SM = 0;                    // 4096
constexpr size_t O_DS = 4096;                 // 4096
constexpr size_t O_GP = 8192;                 // 64
constexpr size_t O_SG = 8256;                 // 4096
constexpr size_t O_AG = 12352;                // 4096
constexpr size_t O_FG = 16448;                // 4096
constexpr size_t O_CTX = 20544;               // 257 (pad 320)
constexpr size_t O_HS = 20864;                // 2097152
constexpr size_t O_NM = O_HS + 2097152;       // 2097152
constexpr size_t O_LB = O_NM + 2097152;       // 262144
constexpr size_t O_AB = O_LB + 262144;        // 1048576
constexpr size_t O_AT = O_AB + 1048576;       // 1048576
constexpr size_t O_A3 = O_AT + 1048576;       // 1048576
constexpr size_t O_SC = O_A3 + 1048576;       // 196608
constexpr size_t O_Y0 = O_SC + 196608;        // 524288
constexpr size_t O_YC = O_Y0 + 524288;        // 1572864
constexpr size_t O_ZB = O_YC + 1572864;       // 524288
constexpr size_t O_GM = O_ZB + 524288;        // 4096
constexpr size_t O_GLV = O_GM + 4096;         // 4096
// total ≈ 10.45 M floats ≈ 41.8 MB

}  // namespace

extern "C" void kernel_launch(void* const* d_in, const int* in_sizes, int n_in,
                              void* d_out, int out_size, void* d_ws,
                              size_t ws_size, hipStream_t stream) {
  (void)in_sizes; (void)n_in; (void)out_size; (void)ws_size;
  const float* x = (const float*)d_in[0];
  const float* gW1 = (const float*)d_in[1];
  const float* gb1 = (const float*)d_in[2];
  const float* g_ln_w = (const float*)d_in[3];
  const float* g_ln_b = (const float*)d_in[4];
  const float* gW2 = (const float*)d_in[5];
  const float* gb2 = (const float*)d_in[6];
  const float* sW1 = (const float*)d_in[7];
  const float* sb1 = (const float*)d_in[8];
  const float* sW2 = (const float*)d_in[9];
  const float* sb2 = (const float*)d_in[10];
  const float* aW1 = (const float*)d_in[11];
  const float* ab1 = (const float*)d_in[12];
  const float* aW2 = (const float*)d_in[13];
  const float* ab2 = (const float*)d_in[14];
  const float* g2f = (const float*)d_in[18];
  const float* sector_emb = (const float*)d_in[19];
  const float* asset_emb = (const float*)d_in[20];
  const float* decay_f = (const float*)d_in[21];
  const float* decay_b = (const float*)d_in[22];
  const float* tW = (const float*)d_in[23];
  const float* tb = (const float*)d_in[24];
  const float* psi = (const float*)d_in[25];
  const float* log_sigma = (const float*)d_in[26];
  const float* step_logits = (const float*)d_in[27];
  const float* noise_scale = (const float*)d_in[28];
  const float* Wk = (const float*)d_in[29];
  const float* mean_w = (const float*)d_in[30];
  const float* mean_b = (const float*)d_in[31];
  const float* lv_w = (const float*)d_in[32];
  const float* lv_b = (const float*)d_in[33];
  const float* dW1 = (const float*)d_in[34];
  const float* db1 = (const float*)d_in[35];
  const float* d_ln_w = (const float*)d_in[36];
  const float* d_ln_b = (const float*)d_in[37];
  const float* mW = (const float*)d_in[38];
  const float* mb = (const float*)d_in[39];
  const float* lvW = (const float*)d_in[40];
  const float* lvb = (const float*)d_in[41];
  float* out = (float*)d_out;
  float* w = (float*)d_ws;

  const uint32_t dka[3] = {DK0.a, DK1.a, DK2.a};
  const uint32_t dkb[3] = {DK0.b, DK1.b, DK2.b};

  // regime controller
  k_reduce_x<<<64, 64, 0, stream>>>(x, w + O_SM, w + O_DS);
  k_g_head<<<16, 256, 0, stream>>>(w + O_SM, gW1, gb1, g_ln_w, g_ln_b, gW2, gb2,
                                   w + O_GP);
  k_s_head<<<16, 256, 0, stream>>>(w + O_SM, sW1, sb1, sW2, sb2, sector_emb,
                                   w + O_SG);
  k_a_head<<<16, 256, 0, stream>>>(w + O_DS, aW1, ab1, aW2, ab2, asset_emb,
                                   w + O_AG);
  k_fgate<<<16, 256, 0, stream>>>(w + O_GP, g2f, w + O_SG, w + O_AG, w + O_FG);
  k_ctx<<<1, 256, 0, stream>>>(w + O_FG, w + O_CTX);

  // temporal scan + projection (writes node_major transposed)
  k_scan<<<64, 64, 0, stream>>>(x, w + O_FG, decay_f, decay_b, w + O_HS);
  gemm_f32<true, true, false><<<dim3(Dn / 32, Tn / 32, Bn), 256, 0, stream>>>(
      w + O_HS, 131072, tW, 0, w + O_NM, 131072, nullptr, 0, tb, Tn, Dn, Dn);

  // Bayesian adjacency + diffusion
  k_adj<<<Hn * Dn, 256, 0, stream>>>(psi, w + O_LB);
  k_a_init<<<MCn * Hn * Dn, 256, 0, stream>>>(w + O_LB, log_sigma, w + O_AB);
  for (int s = 0; s < 3; ++s) {
    k_mix<<<4096, 256, 0, stream>>>(w + O_AB, w + O_AT, w + O_CTX, step_logits,
                                    noise_scale, s, dka[s], dkb[s]);
    k_sym_softmax<<<4096, 256, 0, stream>>>(w + O_AT, w + O_AB);
  }

  // A^2, A^3 (batched over mh), then S_k = mean_mh(A^k)
  gemm_f32<false, false, false><<<dim3(8, 8, 16), 256, 0, stream>>>(
      w + O_AB, 65536, w + O_AB, 65536, w + O_AT, 65536, nullptr, 0, nullptr,
      256, 256, 256);
  gemm_f32<false, false, false><<<dim3(8, 8, 16), 256, 0, stream>>>(
      w + O_AT, 65536, w + O_AB, 65536, w + O_A3, 65536, nullptr, 0, nullptr,
      256, 256, 256);
  k_sreduce<<<768, 256, 0, stream>>>(w + O_AB, w + O_AT, w + O_A3, w + O_SC);

  // Y_k[b] = node_major[b] @ Wk[k]
  for (int k = 0; k < 4; ++k) {
    float* Cp = (k == 0) ? (w + O_Y0) : (w + O_YC + (size_t)(k - 1) * 32768);
    size_t cs = (k == 0) ? 32768 : 98304;
    gemm_f32<false, false, false><<<dim3(4, 8, 16), 256, 0, stream>>>(
        w + O_NM, 131072, Wk + (size_t)k * 65536, 0, Cp, cs, nullptr, 0,
        nullptr, 256, 128, 512);
  }
  // Z[b] = Y0[b] + Scat @ Ycat[b]
  gemm_f32<false, false, true><<<dim3(4, 8, 16), 256, 0, stream>>>(
      w + O_SC, 0, w + O_YC, 98304, w + O_ZB, 32768, w + O_Y0, 32768, nullptr,
      256, 128, 768);

  // heads + decoder
  k_graph_head<<<16, 256, 0, stream>>>(w + O_ZB, mean_w, mean_b, lv_w, lv_b,
                                       w + O_GM, w + O_GLV);
  k_decoder<<<16, 128, 0, stream>>>(w + O_GM, w + O_GLV, dW1, db1, d_ln_w,
                                    d_ln_b, mW, mb, lvW, lvb, out);
}

// Round 2
// 396.991 us; speedup vs baseline: 1.6054x; 1.6054x over previous
//
#include <hip/hip_runtime.h>
#include <stdint.h>

#define PARTITIONABLE 1

namespace {

constexpr int GSn = 4, SSn = 6, ASn = 4;

// ---------------- Threefry-2x32 (constexpr, host+device) ----------------
struct TFPair { uint32_t a, b; };

__host__ __device__ constexpr uint32_t rotl32(uint32_t x, int d) {
  return (x << d) | (x >> (32 - d));
}

__host__ __device__ constexpr TFPair tf2x32(uint32_t k0, uint32_t k1,
                                            uint32_t x0, uint32_t x1) {
  uint32_t k2 = k0 ^ k1 ^ 0x1BD11BDAu;
  x0 += k0; x1 += k1;
  x0 += x1; x1 = rotl32(x1, 13); x1 ^= x0;
  x0 += x1; x1 = rotl32(x1, 15); x1 ^= x0;
  x0 += x1; x1 = rotl32(x1, 26); x1 ^= x0;
  x0 += x1; x1 = rotl32(x1, 6);  x1 ^= x0;
  x0 += k1; x1 += k2 + 1u;
  x0 += x1; x1 = rotl32(x1, 17); x1 ^= x0;
  x0 += x1; x1 = rotl32(x1, 29); x1 ^= x0;
  x0 += x1; x1 = rotl32(x1, 16); x1 ^= x0;
  x0 += x1; x1 = rotl32(x1, 24); x1 ^= x0;
  x0 += k2; x1 += k0 + 2u;
  x0 += x1; x1 = rotl32(x1, 13); x1 ^= x0;
  x0 += x1; x1 = rotl32(x1, 15); x1 ^= x0;
  x0 += x1; x1 = rotl32(x1, 26); x1 ^= x0;
  x0 += x1; x1 = rotl32(x1, 6);  x1 ^= x0;
  x0 += k0; x1 += k1 + 3u;
  x0 += x1; x1 = rotl32(x1, 17); x1 ^= x0;
  x0 += x1; x1 = rotl32(x1, 29); x1 ^= x0;
  x0 += x1; x1 = rotl32(x1, 16); x1 ^= x0;
  x0 += x1; x1 = rotl32(x1, 24); x1 ^= x0;
  x0 += k1; x1 += k2 + 4u;
  x0 += x1; x1 = rotl32(x1, 13); x1 ^= x0;
  x0 += x1; x1 = rotl32(x1, 15); x1 ^= x0;
  x0 += x1; x1 = rotl32(x1, 26); x1 ^= x0;
  x0 += x1; x1 = rotl32(x1, 6);  x1 ^= x0;
  x0 += k2; x1 += k0 + 5u;
  return TFPair{x0, x1};
}

#if PARTITIONABLE
constexpr TFPair KG  = tf2x32(0u, 42u, 0u, 0u);
constexpr TFPair KS  = tf2x32(0u, 42u, 0u, 1u);
constexpr TFPair KA  = tf2x32(0u, 42u, 0u, 2u);
constexpr TFPair KE  = tf2x32(0u, 42u, 0u, 3u);
constexpr TFPair KD  = tf2x32(0u, 42u, 0u, 4u);
constexpr TFPair DK0 = tf2x32(KD.a, KD.b, 0u, 0u);
constexpr TFPair DK1 = tf2x32(KD.a, KD.b, 0u, 1u);
constexpr TFPair DK2 = tf2x32(KD.a, KD.b, 0u, 2u);
#else
constexpr TFPair SP0 = tf2x32(0u, 42u, 0u, 5u);
constexpr TFPair SP1 = tf2x32(0u, 42u, 1u, 6u);
constexpr TFPair SP2 = tf2x32(0u, 42u, 2u, 7u);
constexpr TFPair SP3 = tf2x32(0u, 42u, 3u, 8u);
constexpr TFPair SP4 = tf2x32(0u, 42u, 4u, 9u);
constexpr TFPair KG  = TFPair{SP0.a, SP1.a};
constexpr TFPair KS  = TFPair{SP2.a, SP3.a};
constexpr TFPair KA  = TFPair{SP4.a, SP0.b};
constexpr TFPair KE  = TFPair{SP1.b, SP2.b};
constexpr TFPair KD  = TFPair{SP3.b, SP4.b};
constexpr TFPair DP0 = tf2x32(KD.a, KD.b, 0u, 3u);
constexpr TFPair DP1 = tf2x32(KD.a, KD.b, 1u, 4u);
constexpr TFPair DP2 = tf2x32(KD.a, KD.b, 2u, 5u);
constexpr TFPair DK0 = TFPair{DP0.a, DP1.a};
constexpr TFPair DK1 = TFPair{DP2.a, DP0.b};
constexpr TFPair DK2 = TFPair{DP1.b, DP2.b};
#endif

__device__ __forceinline__ uint32_t rbits(uint32_t k0, uint32_t k1,
                                          uint32_t idx, uint32_t half) {
#if PARTITIONABLE
  TFPair t = tf2x32(k0, k1, 0u, idx);
  return t.a ^ t.b;
#else
  if (idx < half) return tf2x32(k0, k1, idx, idx + half).a;
  return tf2x32(k0, k1, idx - half, idx).b;
#endif
}

__device__ __forceinline__ float bits_to_u01(uint32_t bits) {
  return __uint_as_float((bits >> 9) | 0x3F800000u) - 1.0f;
}

__device__ __forceinline__ float gumbel_u(uint32_t k0, uint32_t k1,
                                          uint32_t idx, uint32_t half) {
  const float mn = 1e-6f;
  const float mx = 1.0f - 1e-6f;
  float f = bits_to_u01(rbits(k0, k1, idx, half));
  return fmaxf(mn, f * (mx - mn) + mn);
}

__device__ __forceinline__ float erfinv_f32(float x) {
  float w = -log1pf(-x * x);
  float p;
  if (w < 5.0f) {
    w -= 2.5f;
    p = 2.81022636e-08f;
    p = fmaf(p, w, 3.43273939e-07f);
    p = fmaf(p, w, -3.5233877e-06f);
    p = fmaf(p, w, -4.39150654e-06f);
    p = fmaf(p, w, 0.00021858087f);
    p = fmaf(p, w, -0.00125372503f);
    p = fmaf(p, w, -0.00417768164f);
    p = fmaf(p, w, 0.246640727f);
    p = fmaf(p, w, 1.50140941f);
  } else {
    w = sqrtf(w) - 3.0f;
    p = -0.000200214257f;
    p = fmaf(p, w, 0.000100950558f);
    p = fmaf(p, w, 0.00134934322f);
    p = fmaf(p, w, -0.00367342844f);
    p = fmaf(p, w, 0.00573950773f);
    p = fmaf(p, w, -0.0076224613f);
    p = fmaf(p, w, 0.00943887047f);
    p = fmaf(p, w, 1.00167406f);
    p = fmaf(p, w, 2.83297682f);
  }
  return p * x;
}

__device__ __forceinline__ float normal_from(uint32_t k0, uint32_t k1,
                                             uint32_t idx, uint32_t half) {
  const float lo = -0x1.fffffep-1f;
  float f = bits_to_u01(rbits(k0, k1, idx, half));
  float u = fmaxf(lo, f * 2.0f + lo);
  return 1.41421356237f * erfinv_f32(u);
}

__device__ __forceinline__ float gelu_f(float x) {
  return 0.5f * x * (1.0f + erff(x / 1.4142135623730951f));
}
__device__ __forceinline__ float sigmoid_f(float x) {
  return 1.0f / (1.0f + expf(-x));
}

template <int NT>
__device__ __forceinline__ float bsum(float v, float* red) {
  int t = threadIdx.x;
  red[t] = v; __syncthreads();
  #pragma unroll
  for (int s = NT >> 1; s > 0; s >>= 1) {
    if (t < s) red[t] += red[t + s];
    __syncthreads();
  }
  float r = red[0]; __syncthreads();
  return r;
}
template <int NT>
__device__ __forceinline__ float bmax(float v, float* red) {
  int t = threadIdx.x;
  red[t] = v; __syncthreads();
  #pragma unroll
  for (int s = NT >> 1; s > 0; s >>= 1) {
    if (t < s) red[t] = fmaxf(red[t], red[t + s]);
    __syncthreads();
  }
  float r = red[0]; __syncthreads();
  return r;
}

// ---------------- kernels ----------------

// partial seq sums: grid 128 (b*8+tc), 256 thr (d), 64 t each
__global__ __launch_bounds__(256) void k_reduce_x(const float* __restrict__ x,
                                                  float* __restrict__ ps) {
  int blk = blockIdx.x;
  int b = blk >> 3, tc = blk & 7;
  int d = threadIdx.x;
  const float* xp = x + ((size_t)b * 512 + tc * 64) * 256 + d;
  float s = 0.f;
  for (int i = 0; i < 64; ++i) s += xp[(size_t)i * 256];
  ps[(size_t)blk * 256 + d] = s;
}

__global__ void k_combine(const float* __restrict__ x,
                          const float* __restrict__ ps, float* __restrict__ sm,
                          float* __restrict__ ds) {
  int b = blockIdx.x, d = threadIdx.x;
  float s = 0.f;
  for (int tc = 0; tc < 8; ++tc) s += ps[(size_t)(b * 8 + tc) * 256 + d];
  sm[b * 256 + d] = s / 512.0f;
  const float* xb = x + (size_t)b * 512 * 256 + d;
  ds[b * 256 + d] = (xb[(size_t)511 * 256] - xb[0]) / 511.0f;
}

__global__ __launch_bounds__(256) void k_g_head(
    const float* __restrict__ sm, const float* __restrict__ gW1,
    const float* __restrict__ gb1, const float* __restrict__ glnw,
    const float* __restrict__ glnb, const float* __restrict__ gW2,
    const float* __restrict__ gb2, float* __restrict__ gprobs) {
  __shared__ float red[256];
  __shared__ float smv[256];
  __shared__ float hg[256];
  __shared__ float lg[GSn];
  __shared__ float vals[GSn];
  int b = blockIdx.x, j = threadIdx.x;
  smv[j] = sm[b * 256 + j];
  __syncthreads();
  float h = gb1[j];
  for (int d = 0; d < 256; ++d) h = fmaf(smv[d], gW1[d * 256 + j], h);
  float mean = bsum<256>(h, red) / 256.0f;
  float dv = h - mean;
  float var = bsum<256>(dv * dv, red) / 256.0f;
  float hn = dv / sqrtf(var + 1e-5f) * glnw[j] + glnb[j];
  hg[j] = gelu_f(hn);
  __syncthreads();
  if (j < GSn) {
    float l = gb2[j];
    for (int d = 0; d < 256; ++d) l = fmaf(hg[d], gW2[d * GSn + j], l);
    lg[j] = l;
  }
  __syncthreads();
  if (j < GSn) {
    float u = gumbel_u(KG.a, KG.b, (uint32_t)(b * GSn + j), 32u);
    float g = -logf(-logf(u));
    vals[j] = (lg[j] + g) / 0.5f;
  }
  __syncthreads();
  if (j < GSn) {
    float mx = vals[0];
    #pragma unroll
    for (int s = 1; s < GSn; ++s) mx = fmaxf(mx, vals[s]);
    float sum = 0.f;
    #pragma unroll
    for (int s = 0; s < GSn; ++s) sum += expf(vals[s] - mx);
    gprobs[b * GSn + j] = expf(vals[j] - mx) / sum;
  }
}

__global__ __launch_bounds__(256) void k_s_head(
    const float* __restrict__ sm, const float* __restrict__ sW1,
    const float* __restrict__ sb1, const float* __restrict__ sW2,
    const float* __restrict__ sb2, const float* __restrict__ semb,
    float* __restrict__ sgate) {
  __shared__ float smv[256];
  __shared__ float hg[256];
  int b = blockIdx.x, j = threadIdx.x;
  smv[j] = sm[b * 256 + j];
  __syncthreads();
  float h = sb1[j];
  for (int d = 0; d < 256; ++d) h = fmaf(smv[d], sW1[d * 256 + j], h);
  hg[j] = gelu_f(h);
  __syncthreads();
  int f = j;
  float lg[SSn];
  #pragma unroll
  for (int s = 0; s < SSn; ++s) lg[s] = sb2[f * SSn + s];
  for (int d = 0; d < 256; ++d) {
    float hd = hg[d];
    const float* w = sW2 + (size_t)d * (256 * SSn) + f * SSn;
    #pragma unroll
    for (int s = 0; s < SSn; ++s) lg[s] = fmaf(hd, w[s], lg[s]);
  }
  uint32_t base = (uint32_t)(b * 256 + f) * SSn;
  float vals[SSn];
  #pragma unroll
  for (int s = 0; s < SSn; ++s) {
    float u = gumbel_u(KS.a, KS.b, base + s, 12288u);
    float g = -logf(-logf(u));
    vals[s] = (lg[s] + g) / 0.5f;
  }
  float mx = vals[0];
  #pragma unroll
  for (int s = 1; s < SSn; ++s) mx = fmaxf(mx, vals[s]);
  float sum = 0.f;
  #pragma unroll
  for (int s = 0; s < SSn; ++s) { vals[s] = expf(vals[s] - mx); sum += vals[s]; }
  float sg = 0.f;
  #pragma unroll
  for (int s = 0; s < SSn; ++s) sg += (vals[s] / sum) * semb[s * 256 + f];
  sgate[b * 256 + f] = sg;
}

__global__ __launch_bounds__(256) void k_a_head(
    const float* __restrict__ ds, const float* __restrict__ aW1,
    const float* __restrict__ ab1, const float* __restrict__ aW2,
    const float* __restrict__ ab2, const float* __restrict__ aemb,
    float* __restrict__ agate) {
  __shared__ float dsv[256];
  __shared__ float hg[256];
  int b = blockIdx.x, j = threadIdx.x;
  dsv[j] = ds[b * 256 + j];
  __syncthreads();
  float h = ab1[j];
  for (int d = 0; d < 256; ++d) h = fmaf(dsv[d], aW1[d * 256 + j], h);
  hg[j] = gelu_f(h);
  __syncthreads();
  int f = j;
  float lg[ASn];
  #pragma unroll
  for (int s = 0; s < ASn; ++s) lg[s] = ab2[f * ASn + s];
  for (int d = 0; d < 256; ++d) {
    float hd = hg[d];
    const float* w = aW2 + (size_t)d * (256 * ASn) + f * ASn;
    #pragma unroll
    for (int s = 0; s < ASn; ++s) lg[s] = fmaf(hd, w[s], lg[s]);
  }
  uint32_t base = (uint32_t)(b * 256 + f) * ASn;
  float vals[ASn];
  #pragma unroll
  for (int s = 0; s < ASn; ++s) {
    float u = gumbel_u(KA.a, KA.b, base + s, 8192u);
    float g = -logf(-logf(u));
    vals[s] = (lg[s] + g) / 0.5f;
  }
  float mx = vals[0];
  #pragma unroll
  for (int s = 1; s < ASn; ++s) mx = fmaxf(mx, vals[s]);
  float sum = 0.f;
  #pragma unroll
  for (int s = 0; s < ASn; ++s) { vals[s] = expf(vals[s] - mx); sum += vals[s]; }
  float ag = 0.f;
  #pragma unroll
  for (int s = 0; s < ASn; ++s) ag += (vals[s] / sum) * aemb[s * 256 + f];
  agate[b * 256 + f] = ag;
}

__global__ void k_fgate(const float* __restrict__ gprobs,
                        const float* __restrict__ g2f,
                        const float* __restrict__ sgate,
                        const float* __restrict__ agate,
                        float* __restrict__ fg) {
  int idx = blockIdx.x * 256 + threadIdx.x;
  int b = idx >> 8, f = idx & 255;
  float gg = 0.f;
  #pragma unroll
  for (int s = 0; s < GSn; ++s) gg = fmaf(gprobs[b * GSn + s], g2f[s * 256 + f], gg);
  fg[idx] = sigmoid_f(gg + sgate[idx] + agate[idx]);
}

__global__ __launch_bounds__(256) void k_ctx(const float* __restrict__ fg,
                                             float* __restrict__ ctx) {
  __shared__ float red[256];
  int f = threadIdx.x;
  float c = 0.f;
  for (int b = 0; b < 16; ++b) c += fg[b * 256 + f];
  c /= 16.0f;
  float ss = bsum<256>(c * c, red);
  float cv = c / (sqrtf(ss) + 1e-6f);
  ctx[f] = cv;
  float S = bsum<256>(cv, red);
  if (f == 0) ctx[256] = S;
}

// v_j[t] = Wk[k]·(mean_w|lv_w), sv_j = sum_t v_j[t]; j = k*2+proj
__global__ __launch_bounds__(512) void k_vcompute(const float* __restrict__ Wk,
                                                  const float* __restrict__ mean_w,
                                                  const float* __restrict__ lv_w,
                                                  float* __restrict__ v,
                                                  float* __restrict__ sv) {
  __shared__ float red[512];
  int j = blockIdx.x, t = threadIdx.x;
  const float* wp = (j & 1) ? lv_w : mean_w;
  const float* wk = Wk + (size_t)(j >> 1) * 65536 + (size_t)t * 128;
  float s = 0.f;
  for (int e = 0; e < 128; ++e) s = fmaf(wk[e], wp[e], s);
  v[j * 512 + t] = s;
  float tot = bsum<512>(s, red);
  if (t == 0) sv[j] = tot;
}

// chunked bidirectional EMA scan, pass 1: per-chunk local P/Q/L
// grid 256 (b*16+c), 256 thr (d); chunk length 32
__global__ __launch_bounds__(256) void k_scan1(
    const float* __restrict__ x, const float* __restrict__ fg,
    const float* __restrict__ decay_f, const float* __restrict__ decay_b,
    const float* __restrict__ v, float* __restrict__ Pf, float* __restrict__ Qf,
    float* __restrict__ Pb, float* __restrict__ Qb, float* __restrict__ Lf,
    float* __restrict__ Lb) {
  __shared__ float vv[8][32];
  int blk = blockIdx.x;
  int b = blk >> 4, c = blk & 15;
  int d = threadIdx.x;
  { int j = d >> 5, i = d & 31; vv[j][i] = v[j * 512 + c * 32 + i]; }
  __syncthreads();
  float g = fg[b * 256 + d];
  float af = sigmoid_f(decay_f[d]);
  float ab = sigmoid_f(decay_b[d]);
  float r_gx[32];
  const float* xp = x + ((size_t)b * 512 + c * 32) * 256 + d;
  #pragma unroll
  for (int i = 0; i < 32; ++i) r_gx[i] = xp[(size_t)i * 256] * g;
  // forward-local
  float h = 0.f, pw = 1.f;
  float P[8], Q[8];
  #pragma unroll
  for (int j = 0; j < 8; ++j) { P[j] = 0.f; Q[j] = 0.f; }
  #pragma unroll
  for (int i = 0; i < 32; ++i) {
    h = fmaf(af, h, (1.0f - af) * r_gx[i]);
    pw *= af;
    #pragma unroll
    for (int j = 0; j < 8; ++j) {
      float vj = vv[j][i];
      P[j] = fmaf(h, vj, P[j]);
      Q[j] = fmaf(pw, vj, Q[j]);
    }
  }
  size_t base = ((size_t)(b * 16 + c) * 8) * 256 + d;
  #pragma unroll
  for (int j = 0; j < 8; ++j) { Pf[base + j * 256] = P[j]; Qf[base + j * 256] = Q[j]; }
  Lf[(b * 16 + c) * 256 + d] = h;
  // backward-local
  h = 0.f; pw = 1.f;
  #pragma unroll
  for (int j = 0; j < 8; ++j) { P[j] = 0.f; Q[j] = 0.f; }
  #pragma unroll
  for (int i = 31; i >= 0; --i) {
    h = fmaf(ab, h, (1.0f - ab) * r_gx[i]);
    pw *= ab;
    #pragma unroll
    for (int j = 0; j < 8; ++j) {
      float vj = vv[j][i];
      P[j] = fmaf(h, vj, P[j]);
      Q[j] = fmaf(pw, vj, Q[j]);
    }
  }
  #pragma unroll
  for (int j = 0; j < 8; ++j) { Pb[base + j * 256] = P[j]; Qb[base + j * 256] = Q[j]; }
  Lb[(b * 16 + c) * 256 + d] = h;
}

// pass 2: combine carries -> u[b][j][d]. grid 128 (b*8+j), 256 thr
__global__ __launch_bounds__(256) void k_scan2(
    const float* __restrict__ Pf, const float* __restrict__ Qf,
    const float* __restrict__ Pb, const float* __restrict__ Qb,
    const float* __restrict__ Lf, const float* __restrict__ Lb,
    const float* __restrict__ decay_f, const float* __restrict__ decay_b,
    float* __restrict__ u) {
  int blk = blockIdx.x;
  int b = blk >> 3, j = blk & 7;
  int d = threadIdx.x;
  float af = sigmoid_f(decay_f[d]);
  float ab = sigmoid_f(decay_b[d]);
  float af32 = af, ab32 = ab;
  #pragma unroll
  for (int q = 0; q < 5; ++q) { af32 *= af32; ab32 *= ab32; }
  float acc = 0.f, H = 0.f;
  for (int c = 0; c < 16; ++c) {
    size_t base = ((size_t)(b * 16 + c) * 8 + j) * 256 + d;
    acc += Pf[base] + H * Qf[base];
    H = Lf[(b * 16 + c) * 256 + d] + af32 * H;
  }
  H = 0.f;
  for (int c = 15; c >= 0; --c) {
    size_t base = ((size_t)(b * 16 + c) * 8 + j) * 256 + d;
    acc += Pb[base] + H * Qb[base];
    H = Lb[(b * 16 + c) * 256 + d] + ab32 * H;
  }
  u[(b * 8 + j) * 256 + d] = acc;
}

// y_j[b][n] = sum_d tW[d][n] u[b][j][d] + tb[n]*sv[j]; k=0 -> gm/glv init,
// k>=1 -> YH[(k-1)][n][b*2+proj]
__global__ __launch_bounds__(256) void k_yproj(
    const float* __restrict__ u, const float* __restrict__ tW,
    const float* __restrict__ tb, const float* __restrict__ sv,
    const float* __restrict__ mean_b, const float* __restrict__ lv_b,
    float* __restrict__ gm, float* __restrict__ glv, float* __restrict__ YH) {
  __shared__ float us[2048];
  int b = blockIdx.x, n = threadIdx.x;
  #pragma unroll
  for (int r = 0; r < 8; ++r) us[n + r * 256] = u[b * 2048 + n + r * 256];
  __syncthreads();
  float y[8];
  #pragma unroll
  for (int j = 0; j < 8; ++j) y[j] = 0.f;
  for (int d = 0; d < 256; ++d) {
    float tw = tW[d * 256 + n];
    #pragma unroll
    for (int j = 0; j < 8; ++j) y[j] = fmaf(tw, us[j * 256 + d], y[j]);
  }
  float tbn = tb[n];
  gm[b * 256 + n] = y[0] + tbn * sv[0] + mean_b[0];
  glv[b * 256 + n] = y[1] + tbn * sv[1] + lv_b[0];
  #pragma unroll
  for (int k = 1; k <= 3; ++k) {
    YH[(k - 1) * 8192 + n * 32 + b * 2 + 0] = y[2 * k] + tbn * sv[2 * k];
    YH[(k - 1) * 8192 + n * 32 + b * 2 + 1] = y[2 * k + 1] + tbn * sv[2 * k + 1];
  }
}

// A0 = softmax(psi·psi^T/sqrt(10) + sigma*eps); adj logits computed inline
__global__ __launch_bounds__(256) void k_a_init(const float* __restrict__ psi,
                                                const float* __restrict__ log_sigma,
                                                float* __restrict__ A) {
  __shared__ float red[256];
  __shared__ float pn[16];
  int blk = blockIdx.x;  // mh*256 + n
  int mh = blk >> 8, h = mh & 3, n = blk & 255, p = threadIdx.x;
  if (p < 10) pn[p] = psi[(size_t)(h * 256 + n) * 10 + p];
  __syncthreads();
  const float* pp = psi + (size_t)(h * 256 + p) * 10;
  float s = 0.f;
  #pragma unroll
  for (int e = 0; e < 10; ++e) s = fmaf(pn[e], pp[e], s);
  float logit = s / sqrtf(10.0f);
  uint32_t idx = (uint32_t)blk * 256u + (uint32_t)p;
  float eps = normal_from(KE.a, KE.b, idx, 524288u);
  float v = logit + expf(log_sigma[h]) * eps;
  float mx = bmax<256>(v, red);
  float e = expf(v - mx);
  float sum = bsum<256>(e, red);
  A[(size_t)blk * 256 + p] = e / sum;
}

// fused diffusion step: mix (both orientations) + symmetrize + row softmax
__global__ __launch_bounds__(256) void k_mix_sym(
    const float* __restrict__ Ain, float* __restrict__ Aout,
    const float* __restrict__ ctx, const float* __restrict__ step_logits,
    const float* __restrict__ noise_scale, int s, uint32_t dk0, uint32_t dk1) {
  __shared__ float red[256];
  int blk = blockIdx.x;  // mh*256 + n
  int mh = blk >> 8, n = blk & 255, p = threadIdx.x;
  float alpha = sigmoid_f(step_logits[s]);
  float ns = noise_scale[s];
  float cn = ctx[n], cp = ctx[p], S = ctx[256];
  float o_np = (cn * cp) / fmaxf(cn * S, 1e-6f);
  float o_pn = (cp * cn) / fmaxf(cp * S, 1e-6f);
  uint32_t i_np = (uint32_t)blk * 256u + (uint32_t)p;
  uint32_t i_pn = (uint32_t)mh * 65536u + (uint32_t)p * 256u + (uint32_t)n;
  float a_np = Ain[(size_t)mh * 65536 + n * 256 + p];
  float a_pn = Ain[(size_t)mh * 65536 + p * 256 + n];
  float m_np = alpha * a_np + (1.0f - alpha) * o_np +
               ns * normal_from(dk0, dk1, i_np, 524288u);
  float m_pn = alpha * a_pn + (1.0f - alpha) * o_pn +
               ns * normal_from(dk0, dk1, i_pn, 524288u);
  float v = 0.5f * (m_np + m_pn);
  float mx = bmax<256>(v, red);
  float e = expf(v - mx);
  float sum = bsum<256>(e, red);
  Aout[(size_t)blk * 256 + p] = e / sum;
}

// one Horner step: Rout[mh] = A[mh] @ Rin[mh or shared] (+Yadd)
// grid (ntile=8, mh=16), 256 thr; 32 cols = b*2+proj
__global__ __launch_bounds__(256) void k_horner(
    const float* __restrict__ A, const float* __restrict__ Rin, int sRin,
    const float* __restrict__ Yadd, float* __restrict__ Rout) {
  int nt = blockIdx.x, mh = blockIdx.y;
  int n0 = nt * 32;
  __shared__ float As[32][33];
  __shared__ float Bs[32][33];
  int tid = threadIdx.x, tx = tid & 31, ty = tid >> 5;
  float acc[4] = {0.f, 0.f, 0.f, 0.f};
  const float* Ab = A + (size_t)mh * 65536;
  const float* Rb = Rin + (size_t)mh * sRin;
  for (int k0 = 0; k0 < 256; k0 += 32) {
    #pragma unroll
    for (int l = 0; l < 4; ++l) {
      int e = tid + l * 256, r = e >> 5, cc = e & 31;
      As[r][cc] = Ab[(size_t)(n0 + r) * 256 + k0 + cc];
      Bs[r][cc] = Rb[(size_t)(k0 + r) * 32 + cc];
    }
    __syncthreads();
    #pragma unroll
    for (int kk = 0; kk < 32; ++kk) {
      float bv = Bs[kk][tx];
      #pragma unroll
      for (int i = 0; i < 4; ++i) acc[i] = fmaf(As[ty + 8 * i][kk], bv, acc[i]);
    }
    __syncthreads();
  }
  #pragma unroll
  for (int i = 0; i < 4; ++i) {
    int n = n0 + ty + 8 * i;
    float v = acc[i];
    if (Yadd) v += Yadd[n * 32 + tx];
    Rout[(size_t)mh * 8192 + (size_t)n * 32 + tx] = v;
  }
}

// gm/glv += mean over mh of R[mh][n][b*2+proj]
__global__ void k_final(const float* __restrict__ R, float* __restrict__ gm,
                        float* __restrict__ glv) {
  int b = blockIdx.x, n = threadIdx.x;
  float sm_ = 0.f, sl = 0.f;
  for (int mh = 0; mh < 16; ++mh) {
    sm_ += R[(size_t)mh * 8192 + n * 32 + b * 2];
    sl += R[(size_t)mh * 8192 + n * 32 + b * 2 + 1];
  }
  gm[b * 256 + n] += sm_ * (1.0f / 16.0f);
  glv[b * 256 + n] += sl * (1.0f / 16.0f);
}

__global__ __launch_bounds__(128) void k_decoder(
    const float* __restrict__ gm, const float* __restrict__ glv,
    const float* __restrict__ dW1, const float* __restrict__ db1,
    const float* __restrict__ dlnw, const float* __restrict__ dlnb,
    const float* __restrict__ mW, const float* __restrict__ mb,
    const float* __restrict__ lvW, const float* __restrict__ lvb,
    float* __restrict__ out) {
  __shared__ float red[128];
  __shared__ float gmv[256];
  int b = blockIdx.x, j = threadIdx.x;
  gmv[j] = gm[b * 256 + j];
  gmv[j + 128] = gm[b * 256 + j + 128];
  __syncthreads();
  float h = db1[j];
  for (int n = 0; n < 256; ++n) h = fmaf(gmv[n], dW1[n * 128 + j], h);
  h = gelu_f(h);
  float mean = bsum<128>(h, red) / 128.0f;
  float dv = h - mean;
  float var = bsum<128>(dv * dv, red) / 128.0f;
  float feat = dv / sqrtf(var + 1e-5f) * dlnw[j] + dlnb[j];
  float m_c = bsum<128>(feat * mW[j], red) + mb[0];
  float lv_c = bsum<128>(feat * lvW[j], red) + lvb[0];
  float se = expf(glv[b * 256 + j]) + expf(glv[b * 256 + j + 128]);
  float sumexp = bsum<128>(se, red);
  if (j == 0) {
    out[b * 2 + 0] = m_c;
    out[b * 2 + 1] = logf(expf(lv_c) + sumexp);
  }
}

// workspace layout (float offsets)
constexpr size_t O_SM = 0;            // 4096
constexpr size_t O_DS = 4096;         // 4096
constexpr size_t O_PS = 8192;         // 32768
constexpr size_t O_GP = 40960;        // 64
constexpr size_t O_SG = 41024;        // 4096
constexpr size_t O_AG = 45120;        // 4096
constexpr size_t O_FG = 49216;        // 4096
constexpr size_t O_CTX = 53312;       // 320
constexpr size_t O_V = 53632;         // 4096
constexpr size_t O_SV = 57728;        // 64
constexpr size_t O_U = 57792;         // 32768
constexpr size_t O_PF = 90560;        // 524288
constexpr size_t O_QF = 614848;       // 524288
constexpr size_t O_PB = 1139136;      // 524288
constexpr size_t O_QB = 1663424;      // 524288
constexpr size_t O_LF = 2187712;      // 65536
constexpr size_t O_LB = 2253248;      // 65536
constexpr size_t O_YH = 2318784;      // 24576
constexpr size_t O_R1 = 2343360;      // 131072
constexpr size_t O_R2 = 2474432;      // 131072
constexpr size_t O_GM = 2605504;      // 4096
constexpr size_t O_GLV = 2609600;     // 4096
constexpr size_t O_A = 2613696;       // 1048576
constexpr size_t O_A2 = 3662272;      // 1048576
// end = 4710848 floats = 18.8 MB

}  // namespace

extern "C" void kernel_launch(void* const* d_in, const int* in_sizes, int n_in,
                              void* d_out, int out_size, void* d_ws,
                              size_t ws_size, hipStream_t stream) {
  (void)in_sizes; (void)n_in; (void)out_size; (void)ws_size;
  const float* x = (const float*)d_in[0];
  const float* gW1 = (const float*)d_in[1];
  const float* gb1 = (const float*)d_in[2];
  const float* g_ln_w = (const float*)d_in[3];
  const float* g_ln_b = (const float*)d_in[4];
  const float* gW2 = (const float*)d_in[5];
  const float* gb2 = (const float*)d_in[6];
  const float* sW1 = (const float*)d_in[7];
  const float* sb1 = (const float*)d_in[8];
  const float* sW2 = (const float*)d_in[9];
  const float* sb2 = (const float*)d_in[10];
  const float* aW1 = (const float*)d_in[11];
  const float* ab1 = (const float*)d_in[12];
  const float* aW2 = (const float*)d_in[13];
  const float* ab2 = (const float*)d_in[14];
  const float* g2f = (const float*)d_in[18];
  const float* sector_emb = (const float*)d_in[19];
  const float* asset_emb = (const float*)d_in[20];
  const float* decay_f = (const float*)d_in[21];
  const float* decay_b = (const float*)d_in[22];
  const float* tW = (const float*)d_in[23];
  const float* tb = (const float*)d_in[24];
  const float* psi = (const float*)d_in[25];
  const float* log_sigma = (const float*)d_in[26];
  const float* step_logits = (const float*)d_in[27];
  const float* noise_scale = (const float*)d_in[28];
  const float* Wk = (const float*)d_in[29];
  const float* mean_w = (const float*)d_in[30];
  const float* mean_b = (const float*)d_in[31];
  const float* lv_w = (const float*)d_in[32];
  const float* lv_b = (const float*)d_in[33];
  const float* dW1 = (const float*)d_in[34];
  const float* db1 = (const float*)d_in[35];
  const float* d_ln_w = (const float*)d_in[36];
  const float* d_ln_b = (const float*)d_in[37];
  const float* mW = (const float*)d_in[38];
  const float* mb = (const float*)d_in[39];
  const float* lvW = (const float*)d_in[40];
  const float* lvb = (const float*)d_in[41];
  float* out = (float*)d_out;
  float* w = (float*)d_ws;

  const uint32_t dka[3] = {DK0.a, DK1.a, DK2.a};
  const uint32_t dkb[3] = {DK0.b, DK1.b, DK2.b};

  // regime controller
  k_reduce_x<<<128, 256, 0, stream>>>(x, w + O_PS);
  k_combine<<<16, 256, 0, stream>>>(x, w + O_PS, w + O_SM, w + O_DS);
  k_g_head<<<16, 256, 0, stream>>>(w + O_SM, gW1, gb1, g_ln_w, g_ln_b, gW2, gb2,
                                   w + O_GP);
  k_s_head<<<16, 256, 0, stream>>>(w + O_SM, sW1, sb1, sW2, sb2, sector_emb,
                                   w + O_SG);
  k_a_head<<<16, 256, 0, stream>>>(w + O_DS, aW1, ab1, aW2, ab2, asset_emb,
                                   w + O_AG);
  k_fgate<<<16, 256, 0, stream>>>(w + O_GP, g2f, w + O_SG, w + O_AG, w + O_FG);
  k_ctx<<<1, 256, 0, stream>>>(w + O_FG, w + O_CTX);

  // Bayesian adjacency + diffusion (A ping-pong, final in O_A2)
  k_a_init<<<4096, 256, 0, stream>>>(psi, log_sigma, w + O_A);
  const size_t asrc[3] = {O_A, O_A2, O_A};
  const size_t adst[3] = {O_A2, O_A, O_A2};
  for (int s = 0; s < 3; ++s) {
    k_mix_sym<<<4096, 256, 0, stream>>>(w + asrc[s], w + adst[s], w + O_CTX,
                                        step_logits, noise_scale, s, dka[s],
                                        dkb[s]);
  }

  // projection vectors + fused scan/contract
  k_vcompute<<<8, 512, 0, stream>>>(Wk, mean_w, lv_w, w + O_V, w + O_SV);
  k_scan1<<<256, 256, 0, stream>>>(x, w + O_FG, decay_f, decay_b, w + O_V,
                                   w + O_PF, w + O_QF, w + O_PB, w + O_QB,
                                   w + O_LF, w + O_LB);
  k_scan2<<<128, 256, 0, stream>>>(w + O_PF, w + O_QF, w + O_PB, w + O_QB,
                                   w + O_LF, w + O_LB, decay_f, decay_b,
                                   w + O_U);
  k_yproj<<<16, 256, 0, stream>>>(w + O_U, tW, tb, w + O_SV, mean_b, lv_b,
                                  w + O_GM, w + O_GLV, w + O_YH);

  // Horner K-hop matvecs: R = A(A(A*y3 + y2) + y1)
  k_horner<<<dim3(8, 16), 256, 0, stream>>>(w + O_A2, w + O_YH + 2 * 8192, 0,
                                            w + O_YH + 1 * 8192, w + O_R1);
  k_horner<<<dim3(8, 16), 256, 0, stream>>>(w + O_A2, w + O_R1, 8192, w + O_YH,
                                            w + O_R2);
  k_horner<<<dim3(8, 16), 256, 0, stream>>>(w + O_A2, w + O_R2, 8192, nullptr,
                                            w + O_R1);
  k_final<<<16, 256, 0, stream>>>(w + O_R1, w + O_GM, w + O_GLV);

  // decoder
  k_decoder<<<16, 128, 0, stream>>>(w + O_GM, w + O_GLV, dW1, db1, d_ln_w,
                                    d_ln_b, mW, mb, lvW, lvb, out);
}

// Round 3
// 358.637 us; speedup vs baseline: 1.7771x; 1.1069x over previous
//
#include <hip/hip_runtime.h>
#include <stdint.h>

#define PARTITIONABLE 1

namespace {

constexpr int GSn = 4, SSn = 6, ASn = 4;

// ---------------- Threefry-2x32 (constexpr, host+device) ----------------
struct TFPair { uint32_t a, b; };

__host__ __device__ constexpr uint32_t rotl32(uint32_t x, int d) {
  return (x << d) | (x >> (32 - d));
}

__host__ __device__ constexpr TFPair tf2x32(uint32_t k0, uint32_t k1,
                                            uint32_t x0, uint32_t x1) {
  uint32_t k2 = k0 ^ k1 ^ 0x1BD11BDAu;
  x0 += k0; x1 += k1;
  x0 += x1; x1 = rotl32(x1, 13); x1 ^= x0;
  x0 += x1; x1 = rotl32(x1, 15); x1 ^= x0;
  x0 += x1; x1 = rotl32(x1, 26); x1 ^= x0;
  x0 += x1; x1 = rotl32(x1, 6);  x1 ^= x0;
  x0 += k1; x1 += k2 + 1u;
  x0 += x1; x1 = rotl32(x1, 17); x1 ^= x0;
  x0 += x1; x1 = rotl32(x1, 29); x1 ^= x0;
  x0 += x1; x1 = rotl32(x1, 16); x1 ^= x0;
  x0 += x1; x1 = rotl32(x1, 24); x1 ^= x0;
  x0 += k2; x1 += k0 + 2u;
  x0 += x1; x1 = rotl32(x1, 13); x1 ^= x0;
  x0 += x1; x1 = rotl32(x1, 15); x1 ^= x0;
  x0 += x1; x1 = rotl32(x1, 26); x1 ^= x0;
  x0 += x1; x1 = rotl32(x1, 6);  x1 ^= x0;
  x0 += k0; x1 += k1 + 3u;
  x0 += x1; x1 = rotl32(x1, 17); x1 ^= x0;
  x0 += x1; x1 = rotl32(x1, 29); x1 ^= x0;
  x0 += x1; x1 = rotl32(x1, 16); x1 ^= x0;
  x0 += x1; x1 = rotl32(x1, 24); x1 ^= x0;
  x0 += k1; x1 += k2 + 4u;
  x0 += x1; x1 = rotl32(x1, 13); x1 ^= x0;
  x0 += x1; x1 = rotl32(x1, 15); x1 ^= x0;
  x0 += x1; x1 = rotl32(x1, 26); x1 ^= x0;
  x0 += x1; x1 = rotl32(x1, 6);  x1 ^= x0;
  x0 += k2; x1 += k0 + 5u;
  return TFPair{x0, x1};
}

#if PARTITIONABLE
constexpr TFPair KG  = tf2x32(0u, 42u, 0u, 0u);
constexpr TFPair KS  = tf2x32(0u, 42u, 0u, 1u);
constexpr TFPair KA  = tf2x32(0u, 42u, 0u, 2u);
constexpr TFPair KE  = tf2x32(0u, 42u, 0u, 3u);
constexpr TFPair KD  = tf2x32(0u, 42u, 0u, 4u);
constexpr TFPair DK0 = tf2x32(KD.a, KD.b, 0u, 0u);
constexpr TFPair DK1 = tf2x32(KD.a, KD.b, 0u, 1u);
constexpr TFPair DK2 = tf2x32(KD.a, KD.b, 0u, 2u);
#else
constexpr TFPair SP0 = tf2x32(0u, 42u, 0u, 5u);
constexpr TFPair SP1 = tf2x32(0u, 42u, 1u, 6u);
constexpr TFPair SP2 = tf2x32(0u, 42u, 2u, 7u);
constexpr TFPair SP3 = tf2x32(0u, 42u, 3u, 8u);
constexpr TFPair SP4 = tf2x32(0u, 42u, 4u, 9u);
constexpr TFPair KG  = TFPair{SP0.a, SP1.a};
constexpr TFPair KS  = TFPair{SP2.a, SP3.a};
constexpr TFPair KA  = TFPair{SP4.a, SP0.b};
constexpr TFPair KE  = TFPair{SP1.b, SP2.b};
constexpr TFPair KD  = TFPair{SP3.b, SP4.b};
constexpr TFPair DP0 = tf2x32(KD.a, KD.b, 0u, 3u);
constexpr TFPair DP1 = tf2x32(KD.a, KD.b, 1u, 4u);
constexpr TFPair DP2 = tf2x32(KD.a, KD.b, 2u, 5u);
constexpr TFPair DK0 = TFPair{DP0.a, DP1.a};
constexpr TFPair DK1 = TFPair{DP2.a, DP0.b};
constexpr TFPair DK2 = TFPair{DP1.b, DP2.b};
#endif

__device__ __forceinline__ uint32_t rbits(uint32_t k0, uint32_t k1,
                                          uint32_t idx, uint32_t half) {
#if PARTITIONABLE
  TFPair t = tf2x32(k0, k1, 0u, idx);
  return t.a ^ t.b;
#else
  if (idx < half) return tf2x32(k0, k1, idx, idx + half).a;
  return tf2x32(k0, k1, idx - half, idx).b;
#endif
}

__device__ __forceinline__ float bits_to_u01(uint32_t bits) {
  return __uint_as_float((bits >> 9) | 0x3F800000u) - 1.0f;
}

__device__ __forceinline__ float gumbel_u(uint32_t k0, uint32_t k1,
                                          uint32_t idx, uint32_t half) {
  const float mn = 1e-6f;
  const float mx = 1.0f - 1e-6f;
  float f = bits_to_u01(rbits(k0, k1, idx, half));
  return fmaxf(mn, f * (mx - mn) + mn);
}

__device__ __forceinline__ float erfinv_f32(float x) {
  float w = -log1pf(-x * x);
  float p;
  if (w < 5.0f) {
    w -= 2.5f;
    p = 2.81022636e-08f;
    p = fmaf(p, w, 3.43273939e-07f);
    p = fmaf(p, w, -3.5233877e-06f);
    p = fmaf(p, w, -4.39150654e-06f);
    p = fmaf(p, w, 0.00021858087f);
    p = fmaf(p, w, -0.00125372503f);
    p = fmaf(p, w, -0.00417768164f);
    p = fmaf(p, w, 0.246640727f);
    p = fmaf(p, w, 1.50140941f);
  } else {
    w = sqrtf(w) - 3.0f;
    p = -0.000200214257f;
    p = fmaf(p, w, 0.000100950558f);
    p = fmaf(p, w, 0.00134934322f);
    p = fmaf(p, w, -0.00367342844f);
    p = fmaf(p, w, 0.00573950773f);
    p = fmaf(p, w, -0.0076224613f);
    p = fmaf(p, w, 0.00943887047f);
    p = fmaf(p, w, 1.00167406f);
    p = fmaf(p, w, 2.83297682f);
  }
  return p * x;
}

__device__ __forceinline__ float normal_from(uint32_t k0, uint32_t k1,
                                             uint32_t idx, uint32_t half) {
  const float lo = -0x1.fffffep-1f;
  float f = bits_to_u01(rbits(k0, k1, idx, half));
  float u = fmaxf(lo, f * 2.0f + lo);
  return 1.41421356237f * erfinv_f32(u);
}

__device__ __forceinline__ float gelu_f(float x) {
  return 0.5f * x * (1.0f + erff(x / 1.4142135623730951f));
}
__device__ __forceinline__ float sigmoid_f(float x) {
  return 1.0f / (1.0f + expf(-x));
}

// ---------------- wave/block reductions (shuffle-based) ----------------
__device__ __forceinline__ float wave_sum(float v) {
  #pragma unroll
  for (int m = 32; m > 0; m >>= 1) v += __shfl_xor(v, m);
  return v;
}
__device__ __forceinline__ float wave_max(float v) {
  #pragma unroll
  for (int m = 32; m > 0; m >>= 1) v = fmaxf(v, __shfl_xor(v, m));
  return v;
}
// NW waves per block; slots must be a dedicated float[NW] (no reuse without
// an intervening __syncthreads)
template <int NW>
__device__ __forceinline__ float blk_sum(float v, float* slots) {
  v = wave_sum(v);
  int wid = threadIdx.x >> 6;
  if ((threadIdx.x & 63) == 0) slots[wid] = v;
  __syncthreads();
  float r = slots[0];
  #pragma unroll
  for (int i = 1; i < NW; ++i) r += slots[i];
  return r;
}
template <int NW>
__device__ __forceinline__ float blk_max(float v, float* slots) {
  v = wave_max(v);
  int wid = threadIdx.x >> 6;
  if ((threadIdx.x & 63) == 0) slots[wid] = v;
  __syncthreads();
  float r = slots[0];
  #pragma unroll
  for (int i = 1; i < NW; ++i) r = fmaxf(r, slots[i]);
  return r;
}

// ---------------- kernels ----------------

// partial seq sums: grid 256 (b*16+tc), 256 thr (d), 32 t each
__global__ __launch_bounds__(256) void k_reduce_x(const float* __restrict__ x,
                                                  float* __restrict__ ps) {
  int blk = blockIdx.x;
  int b = blk >> 4, tc = blk & 15;
  int d = threadIdx.x;
  const float* xp = x + ((size_t)b * 512 + tc * 32) * 256 + d;
  float s = 0.f;
  for (int i = 0; i < 32; ++i) s += xp[(size_t)i * 256];
  ps[(size_t)blk * 256 + d] = s;
}

__global__ void k_combine(const float* __restrict__ x,
                          const float* __restrict__ ps, float* __restrict__ sm,
                          float* __restrict__ ds) {
  int b = blockIdx.x, d = threadIdx.x;
  float s = 0.f;
  for (int tc = 0; tc < 16; ++tc) s += ps[(size_t)(b * 16 + tc) * 256 + d];
  sm[b * 256 + d] = s / 512.0f;
  const float* xb = x + (size_t)b * 512 * 256 + d;
  ds[b * 256 + d] = (xb[(size_t)511 * 256] - xb[0]) / 511.0f;
}

// hidden layers for all three heads. grid 48 = head*16 + b, 256 thr.
// head 0: gelu(LN(sm@gW1+gb1)) -> hgG ; head 1: gelu(sm@sW1+sb1) -> hgS ;
// head 2: gelu(ds@aW1+ab1) -> hgA
__global__ __launch_bounds__(256) void k_hidden(
    const float* __restrict__ sm, const float* __restrict__ ds,
    const float* __restrict__ gW1, const float* __restrict__ gb1,
    const float* __restrict__ glnw, const float* __restrict__ glnb,
    const float* __restrict__ sW1, const float* __restrict__ sb1,
    const float* __restrict__ aW1, const float* __restrict__ ab1,
    float* __restrict__ hgG, float* __restrict__ hgS,
    float* __restrict__ hgA) {
  __shared__ float inv[256];
  __shared__ float s1[4], s2[4];
  int head = blockIdx.x >> 4, b = blockIdx.x & 15, j = threadIdx.x;
  const float* in = (head == 2) ? ds : sm;
  const float* W1 = (head == 0) ? gW1 : (head == 1) ? sW1 : aW1;
  const float* b1 = (head == 0) ? gb1 : (head == 1) ? sb1 : ab1;
  inv[j] = in[b * 256 + j];
  __syncthreads();
  float h = b1[j];
  for (int d = 0; d < 256; ++d) h = fmaf(inv[d], W1[d * 256 + j], h);
  float* outp = (head == 0) ? hgG : (head == 1) ? hgS : hgA;
  if (head == 0) {
    float mean = blk_sum<4>(h, s1) / 256.0f;
    float dv = h - mean;
    float var = blk_sum<4>(dv * dv, s2) / 256.0f;
    h = dv / sqrtf(var + 1e-5f) * glnw[j] + glnb[j];
  }
  outp[b * 256 + j] = gelu_f(h);
}

// sector second layer + gumbel: grid (16 b, 8 ftile), 192 thr = 32f x 6s
__global__ __launch_bounds__(192) void k_s2(const float* __restrict__ hgS,
                                            const float* __restrict__ sW2,
                                            const float* __restrict__ sb2,
                                            const float* __restrict__ semb,
                                            float* __restrict__ sgate) {
  __shared__ float hs[256];
  __shared__ float lv[32][6];
  int b = blockIdx.x, f0 = blockIdx.y * 32;
  int tid = threadIdx.x;
  int fl = tid / 6, s = tid - fl * 6;
  for (int i = tid; i < 256; i += 192) hs[i] = hgS[b * 256 + i];
  __syncthreads();
  int f = f0 + fl;
  const float* wcol = sW2 + f * 6 + s;
  float acc = sb2[f * 6 + s];
  for (int d = 0; d < 256; ++d) acc = fmaf(hs[d], wcol[(size_t)d * 1536], acc);
  float u = gumbel_u(KS.a, KS.b, (uint32_t)(b * 256 + f) * 6u + s, 12288u);
  float g = -logf(-logf(u));
  lv[fl][s] = (acc + g) / 0.5f;
  __syncthreads();
  if (tid < 32) {
    int ff = f0 + tid;
    float v0 = lv[tid][0], v1 = lv[tid][1], v2 = lv[tid][2];
    float v3 = lv[tid][3], v4 = lv[tid][4], v5 = lv[tid][5];
    float mx = fmaxf(fmaxf(fmaxf(v0, v1), fmaxf(v2, v3)), fmaxf(v4, v5));
    float e0 = expf(v0 - mx), e1 = expf(v1 - mx), e2 = expf(v2 - mx);
    float e3 = expf(v3 - mx), e4 = expf(v4 - mx), e5 = expf(v5 - mx);
    float sum = e0 + e1 + e2 + e3 + e4 + e5;
    float sg = (e0 * semb[0 * 256 + ff] + e1 * semb[1 * 256 + ff] +
                e2 * semb[2 * 256 + ff] + e3 * semb[3 * 256 + ff] +
                e4 * semb[4 * 256 + ff] + e5 * semb[5 * 256 + ff]) / sum;
    sgate[b * 256 + ff] = sg;
  }
}

// asset second layer + gumbel: grid (16 b, 4 ftile), 256 thr = 64f x 4s
__global__ __launch_bounds__(256) void k_a2(const float* __restrict__ hgA,
                                            const float* __restrict__ aW2,
                                            const float* __restrict__ ab2,
                                            const float* __restrict__ aemb,
                                            float* __restrict__ agate) {
  __shared__ float hs[256];
  __shared__ float lv[64][4];
  int b = blockIdx.x, f0 = blockIdx.y * 64;
  int tid = threadIdx.x;
  int fl = tid >> 2, s = tid & 3;
  hs[tid] = hgA[b * 256 + tid];
  __syncthreads();
  int f = f0 + fl;
  const float* wcol = aW2 + f * 4 + s;
  float acc = ab2[f * 4 + s];
  for (int d = 0; d < 256; ++d) acc = fmaf(hs[d], wcol[(size_t)d * 1024], acc);
  float u = gumbel_u(KA.a, KA.b, (uint32_t)(b * 256 + f) * 4u + s, 8192u);
  float g = -logf(-logf(u));
  lv[fl][s] = (acc + g) / 0.5f;
  __syncthreads();
  if (tid < 64) {
    int ff = f0 + tid;
    float v0 = lv[tid][0], v1 = lv[tid][1], v2 = lv[tid][2], v3 = lv[tid][3];
    float mx = fmaxf(fmaxf(v0, v1), fmaxf(v2, v3));
    float e0 = expf(v0 - mx), e1 = expf(v1 - mx);
    float e2 = expf(v2 - mx), e3 = expf(v3 - mx);
    float sum = e0 + e1 + e2 + e3;
    float ag = (e0 * aemb[0 * 256 + ff] + e1 * aemb[1 * 256 + ff] +
                e2 * aemb[2 * 256 + ff] + e3 * aemb[3 * 256 + ff]) / sum;
    agate[b * 256 + ff] = ag;
  }
}

// g second layer + gumbel + feature gate. grid 16, 256 thr.
__global__ __launch_bounds__(256) void k_fgate(
    const float* __restrict__ hgG, const float* __restrict__ gW2,
    const float* __restrict__ gb2, const float* __restrict__ g2f,
    const float* __restrict__ sgate, const float* __restrict__ agate,
    float* __restrict__ fg) {
  __shared__ float slots[4][4];
  __shared__ float vals[4];
  __shared__ float gp[4];
  int b = blockIdx.x, j = threadIdx.x;
  float hj = hgG[b * 256 + j];
  float lg[4];
  #pragma unroll
  for (int s = 0; s < 4; ++s)
    lg[s] = blk_sum<4>(hj * gW2[j * 4 + s], slots[s]);
  if (j < 4) {
    float u = gumbel_u(KG.a, KG.b, (uint32_t)(b * 4 + j), 32u);
    float g = -logf(-logf(u));
    vals[j] = (lg[j] + gb2[j] + g) / 0.5f;
  }
  __syncthreads();
  if (j < 4) {
    float mx = fmaxf(fmaxf(vals[0], vals[1]), fmaxf(vals[2], vals[3]));
    float sum = expf(vals[0] - mx) + expf(vals[1] - mx) + expf(vals[2] - mx) +
                expf(vals[3] - mx);
    gp[j] = expf(vals[j] - mx) / sum;
  }
  __syncthreads();
  int f = j;
  float gg = 0.f;
  #pragma unroll
  for (int s = 0; s < 4; ++s) gg = fmaf(gp[s], g2f[s * 256 + f], gg);
  fg[b * 256 + f] = sigmoid_f(gg + sgate[b * 256 + f] + agate[b * 256 + f]);
}

__global__ __launch_bounds__(256) void k_ctx(const float* __restrict__ fg,
                                             float* __restrict__ ctx) {
  __shared__ float s1[4], s2[4];
  int f = threadIdx.x;
  float c = 0.f;
  for (int b = 0; b < 16; ++b) c += fg[b * 256 + f];
  c /= 16.0f;
  float ss = blk_sum<4>(c * c, s1);
  float cv = c / (sqrtf(ss) + 1e-6f);
  ctx[f] = cv;
  float S = blk_sum<4>(cv, s2);
  if (f == 0) ctx[256] = S;
}

// v_j[t] = Wk[k]·(mean_w|lv_w); grid 32 = j*4+tg, 256 thr (4 waves);
// sv[j] accumulated by atomics (memset to 0 first)
__global__ __launch_bounds__(256) void k_vcompute(const float* __restrict__ Wk,
                                                  const float* __restrict__ mean_w,
                                                  const float* __restrict__ lv_w,
                                                  float* __restrict__ v,
                                                  float* __restrict__ sv) {
  int j = blockIdx.x >> 2, tg = blockIdx.x & 3;
  const float* wp = (j & 1) ? lv_w : mean_w;
  const float* Wkk = Wk + (size_t)(j >> 1) * 65536;
  int wid = threadIdx.x >> 6, lane = threadIdx.x & 63;
  float w0 = wp[lane], w1 = wp[64 + lane];
  float svloc = 0.f;
  for (int i = 0; i < 32; ++i) {
    int t = tg * 128 + wid * 32 + i;
    const float* row = Wkk + (size_t)t * 128;
    float s = row[lane] * w0 + row[64 + lane] * w1;
    s = wave_sum(s);
    if (lane == 0) { v[j * 512 + t] = s; svloc += s; }
  }
  if (lane == 0) atomicAdd(&sv[j], svloc);
}

// chunked bidirectional EMA scan, pass 1 (unchanged from r2)
__global__ __launch_bounds__(256) void k_scan1(
    const float* __restrict__ x, const float* __restrict__ fg,
    const float* __restrict__ decay_f, const float* __restrict__ decay_b,
    const float* __restrict__ v, float* __restrict__ Pf, float* __restrict__ Qf,
    float* __restrict__ Pb, float* __restrict__ Qb, float* __restrict__ Lf,
    float* __restrict__ Lb) {
  __shared__ float vv[8][32];
  int blk = blockIdx.x;
  int b = blk >> 4, c = blk & 15;
  int d = threadIdx.x;
  { int j = d >> 5, i = d & 31; vv[j][i] = v[j * 512 + c * 32 + i]; }
  __syncthreads();
  float g = fg[b * 256 + d];
  float af = sigmoid_f(decay_f[d]);
  float ab = sigmoid_f(decay_b[d]);
  float r_gx[32];
  const float* xp = x + ((size_t)b * 512 + c * 32) * 256 + d;
  #pragma unroll
  for (int i = 0; i < 32; ++i) r_gx[i] = xp[(size_t)i * 256] * g;
  float h = 0.f, pw = 1.f;
  float P[8], Q[8];
  #pragma unroll
  for (int j = 0; j < 8; ++j) { P[j] = 0.f; Q[j] = 0.f; }
  #pragma unroll
  for (int i = 0; i < 32; ++i) {
    h = fmaf(af, h, (1.0f - af) * r_gx[i]);
    pw *= af;
    #pragma unroll
    for (int j = 0; j < 8; ++j) {
      float vj = vv[j][i];
      P[j] = fmaf(h, vj, P[j]);
      Q[j] = fmaf(pw, vj, Q[j]);
    }
  }
  size_t base = ((size_t)(b * 16 + c) * 8) * 256 + d;
  #pragma unroll
  for (int j = 0; j < 8; ++j) { Pf[base + j * 256] = P[j]; Qf[base + j * 256] = Q[j]; }
  Lf[(b * 16 + c) * 256 + d] = h;
  h = 0.f; pw = 1.f;
  #pragma unroll
  for (int j = 0; j < 8; ++j) { P[j] = 0.f; Q[j] = 0.f; }
  #pragma unroll
  for (int i = 31; i >= 0; --i) {
    h = fmaf(ab, h, (1.0f - ab) * r_gx[i]);
    pw *= ab;
    #pragma unroll
    for (int j = 0; j < 8; ++j) {
      float vj = vv[j][i];
      P[j] = fmaf(h, vj, P[j]);
      Q[j] = fmaf(pw, vj, Q[j]);
    }
  }
  #pragma unroll
  for (int j = 0; j < 8; ++j) { Pb[base + j * 256] = P[j]; Qb[base + j * 256] = Q[j]; }
  Lb[(b * 16 + c) * 256 + d] = h;
}

// pass 2 (unchanged)
__global__ __launch_bounds__(256) void k_scan2(
    const float* __restrict__ Pf, const float* __restrict__ Qf,
    const float* __restrict__ Pb, const float* __restrict__ Qb,
    const float* __restrict__ Lf, const float* __restrict__ Lb,
    const float* __restrict__ decay_f, const float* __restrict__ decay_b,
    float* __restrict__ u) {
  int blk = blockIdx.x;
  int b = blk >> 3, j = blk & 7;
  int d = threadIdx.x;
  float af = sigmoid_f(decay_f[d]);
  float ab = sigmoid_f(decay_b[d]);
  float af32 = af, ab32 = ab;
  #pragma unroll
  for (int q = 0; q < 5; ++q) { af32 *= af32; ab32 *= ab32; }
  float acc = 0.f, H = 0.f;
  for (int c = 0; c < 16; ++c) {
    size_t base = ((size_t)(b * 16 + c) * 8 + j) * 256 + d;
    acc += Pf[base] + H * Qf[base];
    H = Lf[(b * 16 + c) * 256 + d] + af32 * H;
  }
  H = 0.f;
  for (int c = 15; c >= 0; --c) {
    size_t base = ((size_t)(b * 16 + c) * 8 + j) * 256 + d;
    acc += Pb[base] + H * Qb[base];
    H = Lb[(b * 16 + c) * 256 + d] + ab32 * H;
  }
  u[(b * 8 + j) * 256 + d] = acc;
}

// tiled GEMM C[row=b*8+j][n] = u[row]·tW[:,n] with fused scatter epilogue
// grid (8 ntile, 4 mtile), 256 thr
__global__ __launch_bounds__(256) void k_ygemm(
    const float* __restrict__ u, const float* __restrict__ tW,
    const float* __restrict__ tb, const float* __restrict__ sv,
    const float* __restrict__ mean_b, const float* __restrict__ lv_b,
    float* __restrict__ gm, float* __restrict__ glv, float* __restrict__ YH) {
  __shared__ float As[32][33];
  __shared__ float Bs[32][33];
  __shared__ float svs[8];
  int n0 = blockIdx.x * 32, m0 = blockIdx.y * 32;
  int tid = threadIdx.x, tx = tid & 31, ty = tid >> 5;
  if (tid < 8) svs[tid] = sv[tid];
  float acc[4] = {0.f, 0.f, 0.f, 0.f};
  for (int k0 = 0; k0 < 256; k0 += 32) {
    #pragma unroll
    for (int l = 0; l < 4; ++l) {
      int e = tid + l * 256, r = e >> 5, cc = e & 31;
      As[r][cc] = u[(size_t)(m0 + r) * 256 + k0 + cc];
      Bs[r][cc] = tW[(size_t)(k0 + r) * 256 + n0 + cc];
    }
    __syncthreads();
    #pragma unroll
    for (int kk = 0; kk < 32; ++kk) {
      float bv = Bs[kk][tx];
      #pragma unroll
      for (int i = 0; i < 4; ++i) acc[i] = fmaf(As[ty + 8 * i][kk], bv, acc[i]);
    }
    __syncthreads();
  }
  int n = n0 + tx;
  float tbn = tb[n];
  float mb0 = mean_b[0], lb0 = lv_b[0];
  #pragma unroll
  for (int i = 0; i < 4; ++i) {
    int row = m0 + ty + 8 * i;
    int b = row >> 3, j = row & 7;
    float val = acc[i] + tbn * svs[j];
    if (j == 0) gm[b * 256 + n] = val + mb0;
    else if (j == 1) glv[b * 256 + n] = val + lb0;
    else {
      int k = (j >> 1) - 1, proj = j & 1;
      YH[k * 8192 + n * 32 + b * 2 + proj] = val;
    }
  }
}

// A0 = softmax(psi·psi^T/sqrt(10) + sigma*eps)
__global__ __launch_bounds__(256) void k_a_init(const float* __restrict__ psi,
                                                const float* __restrict__ log_sigma,
                                                float* __restrict__ A) {
  __shared__ float pn[12];
  __shared__ float s1[4], s2[4];
  int blk = blockIdx.x;  // mh*256 + n
  int mh = blk >> 8, h = mh & 3, n = blk & 255, p = threadIdx.x;
  if (p < 10) pn[p] = psi[(size_t)(h * 256 + n) * 10 + p];
  __syncthreads();
  const float* pp = psi + (size_t)(h * 256 + p) * 10;
  float s = 0.f;
  #pragma unroll
  for (int e = 0; e < 10; ++e) s = fmaf(pn[e], pp[e], s);
  float logit = s / sqrtf(10.0f);
  uint32_t idx = (uint32_t)blk * 256u + (uint32_t)p;
  float eps = normal_from(KE.a, KE.b, idx, 524288u);
  float val = logit + expf(log_sigma[h]) * eps;
  float mx = blk_max<4>(val, s1);
  float e = expf(val - mx);
  float sum = blk_sum<4>(e, s2);
  A[(size_t)blk * 256 + p] = e / sum;
}

// fused diffusion step: mix both orientations + symmetrize + row softmax
__global__ __launch_bounds__(256) void k_mix_sym(
    const float* __restrict__ Ain, float* __restrict__ Aout,
    const float* __restrict__ ctx, const float* __restrict__ step_logits,
    const float* __restrict__ noise_scale, int s, uint32_t dk0, uint32_t dk1) {
  __shared__ float s1[4], s2[4];
  int blk = blockIdx.x;  // mh*256 + n
  int mh = blk >> 8, n = blk & 255, p = threadIdx.x;
  float alpha = sigmoid_f(step_logits[s]);
  float ns = noise_scale[s];
  float cn = ctx[n], cp = ctx[p], S = ctx[256];
  float o_np = (cn * cp) / fmaxf(cn * S, 1e-6f);
  float o_pn = (cp * cn) / fmaxf(cp * S, 1e-6f);
  uint32_t i_np = (uint32_t)blk * 256u + (uint32_t)p;
  uint32_t i_pn = (uint32_t)mh * 65536u + (uint32_t)p * 256u + (uint32_t)n;
  float a_np = Ain[(size_t)mh * 65536 + n * 256 + p];
  float a_pn = Ain[(size_t)mh * 65536 + p * 256 + n];
  float m_np = alpha * a_np + (1.0f - alpha) * o_np +
               ns * normal_from(dk0, dk1, i_np, 524288u);
  float m_pn = alpha * a_pn + (1.0f - alpha) * o_pn +
               ns * normal_from(dk0, dk1, i_pn, 524288u);
  float val = 0.5f * (m_np + m_pn);
  float mx = blk_max<4>(val, s1);
  float e = expf(val - mx);
  float sum = blk_sum<4>(e, s2);
  Aout[(size_t)blk * 256 + p] = e / sum;
}

// Horner step (unchanged)
__global__ __launch_bounds__(256) void k_horner(
    const float* __restrict__ A, const float* __restrict__ Rin, int sRin,
    const float* __restrict__ Yadd, float* __restrict__ Rout) {
  int nt = blockIdx.x, mh = blockIdx.y;
  int n0 = nt * 32;
  __shared__ float As[32][33];
  __shared__ float Bs[32][33];
  int tid = threadIdx.x, tx = tid & 31, ty = tid >> 5;
  float acc[4] = {0.f, 0.f, 0.f, 0.f};
  const float* Ab = A + (size_t)mh * 65536;
  const float* Rb = Rin + (size_t)mh * sRin;
  for (int k0 = 0; k0 < 256; k0 += 32) {
    #pragma unroll
    for (int l = 0; l < 4; ++l) {
      int e = tid + l * 256, r = e >> 5, cc = e & 31;
      As[r][cc] = Ab[(size_t)(n0 + r) * 256 + k0 + cc];
      Bs[r][cc] = Rb[(size_t)(k0 + r) * 32 + cc];
    }
    __syncthreads();
    #pragma unroll
    for (int kk = 0; kk < 32; ++kk) {
      float bv = Bs[kk][tx];
      #pragma unroll
      for (int i = 0; i < 4; ++i) acc[i] = fmaf(As[ty + 8 * i][kk], bv, acc[i]);
    }
    __syncthreads();
  }
  #pragma unroll
  for (int i = 0; i < 4; ++i) {
    int n = n0 + ty + 8 * i;
    float vv = acc[i];
    if (Yadd) vv += Yadd[n * 32 + tx];
    Rout[(size_t)mh * 8192 + (size_t)n * 32 + tx] = vv;
  }
}

__global__ void k_final(const float* __restrict__ R, float* __restrict__ gm,
                        float* __restrict__ glv) {
  int b = blockIdx.x, n = threadIdx.x;
  float sm_ = 0.f, sl = 0.f;
  for (int mh = 0; mh < 16; ++mh) {
    sm_ += R[(size_t)mh * 8192 + n * 32 + b * 2];
    sl += R[(size_t)mh * 8192 + n * 32 + b * 2 + 1];
  }
  gm[b * 256 + n] += sm_ * (1.0f / 16.0f);
  glv[b * 256 + n] += sl * (1.0f / 16.0f);
}

__global__ __launch_bounds__(128) void k_decoder(
    const float* __restrict__ gm, const float* __restrict__ glv,
    const float* __restrict__ dW1, const float* __restrict__ db1,
    const float* __restrict__ dlnw, const float* __restrict__ dlnb,
    const float* __restrict__ mW, const float* __restrict__ mb,
    const float* __restrict__ lvW, const float* __restrict__ lvb,
    float* __restrict__ out) {
  __shared__ float gmv[256];
  __shared__ float s1[2], s2[2], s3[2], s4[2], s5[2];
  int b = blockIdx.x, j = threadIdx.x;
  gmv[j] = gm[b * 256 + j];
  gmv[j + 128] = gm[b * 256 + j + 128];
  __syncthreads();
  float h = db1[j];
  for (int n = 0; n < 256; ++n) h = fmaf(gmv[n], dW1[n * 128 + j], h);
  h = gelu_f(h);
  float mean = blk_sum<2>(h, s1) / 128.0f;
  float dv = h - mean;
  float var = blk_sum<2>(dv * dv, s2) / 128.0f;
  float feat = dv / sqrtf(var + 1e-5f) * dlnw[j] + dlnb[j];
  float m_c = blk_sum<2>(feat * mW[j], s3) + mb[0];
  float lv_c = blk_sum<2>(feat * lvW[j], s4) + lvb[0];
  float se = expf(glv[b * 256 + j]) + expf(glv[b * 256 + j + 128]);
  float sumexp = blk_sum<2>(se, s5);
  if (j == 0) {
    out[b * 2 + 0] = m_c;
    out[b * 2 + 1] = logf(expf(lv_c) + sumexp);
  }
}

// workspace layout (float offsets)
constexpr size_t O_SM = 0;            // 4096
constexpr size_t O_DS = 4096;         // 4096
constexpr size_t O_PS = 8192;         // 65536 (256 blocks x 256)
constexpr size_t O_HGG = 73728;       // 4096
constexpr size_t O_HGS = 77824;       // 4096
constexpr size_t O_HGA = 81920;       // 4096
constexpr size_t O_SG = 86016;        // 4096
constexpr size_t O_AG = 90112;        // 4096
constexpr size_t O_FG = 94208;        // 4096
constexpr size_t O_CTX = 98304;       // 320
constexpr size_t O_V = 98624;         // 4096
constexpr size_t O_SV = 102720;       // 64
constexpr size_t O_U = 102784;        // 32768
constexpr size_t O_PF = 135552;       // 524288
constexpr size_t O_QF = 659840;       // 524288
constexpr size_t O_PB = 1184128;      // 524288
constexpr size_t O_QB = 1708416;      // 524288
constexpr size_t O_LF = 2232704;      // 65536
constexpr size_t O_LB = 2298240;      // 65536
constexpr size_t O_YH = 2363776;      // 24576
constexpr size_t O_R1 = 2388352;      // 131072
constexpr size_t O_R2 = 2519424;      // 131072
constexpr size_t O_GM = 2650496;      // 4096
constexpr size_t O_GLV = 2654592;     // 4096
constexpr size_t O_A = 2658688;       // 1048576
constexpr size_t O_A2 = 3707264;      // 1048576
// end = 4755840 floats = 19.0 MB

}  // namespace

extern "C" void kernel_launch(void* const* d_in, const int* in_sizes, int n_in,
                              void* d_out, int out_size, void* d_ws,
                              size_t ws_size, hipStream_t stream) {
  (void)in_sizes; (void)n_in; (void)out_size; (void)ws_size;
  const float* x = (const float*)d_in[0];
  const float* gW1 = (const float*)d_in[1];
  const float* gb1 = (const float*)d_in[2];
  const float* g_ln_w = (const float*)d_in[3];
  const float* g_ln_b = (const float*)d_in[4];
  const float* gW2 = (const float*)d_in[5];
  const float* gb2 = (const float*)d_in[6];
  const float* sW1 = (const float*)d_in[7];
  const float* sb1 = (const float*)d_in[8];
  const float* sW2 = (const float*)d_in[9];
  const float* sb2 = (const float*)d_in[10];
  const float* aW1 = (const float*)d_in[11];
  const float* ab1 = (const float*)d_in[12];
  const float* aW2 = (const float*)d_in[13];
  const float* ab2 = (const float*)d_in[14];
  const float* g2f = (const float*)d_in[18];
  const float* sector_emb = (const float*)d_in[19];
  const float* asset_emb = (const float*)d_in[20];
  const float* decay_f = (const float*)d_in[21];
  const float* decay_b = (const float*)d_in[22];
  const float* tW = (const float*)d_in[23];
  const float* tb = (const float*)d_in[24];
  const float* psi = (const float*)d_in[25];
  const float* log_sigma = (const float*)d_in[26];
  const float* step_logits = (const float*)d_in[27];
  const float* noise_scale = (const float*)d_in[28];
  const float* Wk = (const float*)d_in[29];
  const float* mean_w = (const float*)d_in[30];
  const float* mean_b = (const float*)d_in[31];
  const float* lv_w = (const float*)d_in[32];
  const float* lv_b = (const float*)d_in[33];
  const float* dW1 = (const float*)d_in[34];
  const float* db1 = (const float*)d_in[35];
  const float* d_ln_w = (const float*)d_in[36];
  const float* d_ln_b = (const float*)d_in[37];
  const float* mW = (const float*)d_in[38];
  const float* mb = (const float*)d_in[39];
  const float* lvW = (const float*)d_in[40];
  const float* lvb = (const float*)d_in[41];
  float* out = (float*)d_out;
  float* w = (float*)d_ws;

  const uint32_t dka[3] = {DK0.a, DK1.a, DK2.a};
  const uint32_t dkb[3] = {DK0.b, DK1.b, DK2.b};

  hipMemsetAsync(w + O_SV, 0, 64 * sizeof(float), stream);

  // regime controller
  k_reduce_x<<<256, 256, 0, stream>>>(x, w + O_PS);
  k_combine<<<16, 256, 0, stream>>>(x, w + O_PS, w + O_SM, w + O_DS);
  k_hidden<<<48, 256, 0, stream>>>(w + O_SM, w + O_DS, gW1, gb1, g_ln_w,
                                   g_ln_b, sW1, sb1, aW1, ab1, w + O_HGG,
                                   w + O_HGS, w + O_HGA);
  k_s2<<<dim3(16, 8), 192, 0, stream>>>(w + O_HGS, sW2, sb2, sector_emb,
                                        w + O_SG);
  k_a2<<<dim3(16, 4), 256, 0, stream>>>(w + O_HGA, aW2, ab2, asset_emb,
                                        w + O_AG);
  k_fgate<<<16, 256, 0, stream>>>(w + O_HGG, gW2, gb2, g2f, w + O_SG, w + O_AG,
                                  w + O_FG);
  k_ctx<<<1, 256, 0, stream>>>(w + O_FG, w + O_CTX);

  // Bayesian adjacency + diffusion (A ping-pong, final in O_A2)
  k_a_init<<<4096, 256, 0, stream>>>(psi, log_sigma, w + O_A);
  const size_t asrc[3] = {O_A, O_A2, O_A};
  const size_t adst[3] = {O_A2, O_A, O_A2};
  for (int s = 0; s < 3; ++s) {
    k_mix_sym<<<4096, 256, 0, stream>>>(w + asrc[s], w + adst[s], w + O_CTX,
                                        step_logits, noise_scale, s, dka[s],
                                        dkb[s]);
  }

  // projection vectors + fused scan/contract
  k_vcompute<<<32, 256, 0, stream>>>(Wk, mean_w, lv_w, w + O_V, w + O_SV);
  k_scan1<<<256, 256, 0, stream>>>(x, w + O_FG, decay_f, decay_b, w + O_V,
                                   w + O_PF, w + O_QF, w + O_PB, w + O_QB,
                                   w + O_LF, w + O_LB);
  k_scan2<<<128, 256, 0, stream>>>(w + O_PF, w + O_QF, w + O_PB, w + O_QB,
                                   w + O_LF, w + O_LB, decay_f, decay_b,
                                   w + O_U);
  k_ygemm<<<dim3(8, 4), 256, 0, stream>>>(w + O_U, tW, tb, w + O_SV, mean_b,
                                          lv_b, w + O_GM, w + O_GLV, w + O_YH);

  // Horner K-hop matvecs: R = A(A(A*y3 + y2) + y1)
  k_horner<<<dim3(8, 16), 256, 0, stream>>>(w + O_A2, w + O_YH + 2 * 8192, 0,
                                            w + O_YH + 1 * 8192, w + O_R1);
  k_horner<<<dim3(8, 16), 256, 0, stream>>>(w + O_A2, w + O_R1, 8192, w + O_YH,
                                            w + O_R2);
  k_horner<<<dim3(8, 16), 256, 0, stream>>>(w + O_A2, w + O_R2, 8192, nullptr,
                                            w + O_R1);
  k_final<<<16, 256, 0, stream>>>(w + O_R1, w + O_GM, w + O_GLV);

  // decoder
  k_decoder<<<16, 128, 0, stream>>>(w + O_GM, w + O_GLV, dW1, db1, d_ln_w,
                                    d_ln_b, mW, mb, lvW, lvb, out);
}